// Round 1
// baseline (6071.822 us; speedup 1.0000x reference)
//
#include <hip/hip_runtime.h>

// Problem constants (fixed by the reference)
#define NSEQ   30000
#define NPAD   30208      // NSEQ + FPAD, multiple of 256
#define FPAD   208        // front padding
#define DMODEL 1024
#define NHEAD  8
#define DHEAD  64
#define LM     256        // landmarks
#define LCHUNK 118        // NPAD / LM
#define INNER  512        // NHEAD*DHEAD

typedef long long ll;

// ---------------------------------------------------------------------------
// Tiled fp32 GEMM: 128x64 block tile, BK=16, 256 threads, 8x4 microtile.
// TB=0: C = A(MxK) @ B(KxN);  TB=1: C = A(MxK) @ B(NxK)^T
// A rows are read at (row + aRowOff); rows outside [0,aMaxRow) read as zero
// (implicit front-padding). Batched via grid.z with strides; optional split-K
// (ksplit>1, EPI==6 atomic accumulate only).
// EPI: 0: C=alpha*acc   1: C=acc+bias[c]   2: C=acc+bias[c]+add[r*ldadd+c]
//      3: qkv scatter to [part][head][row][d] with q*=1/8
//      4: C=diagv*(r==c)-acc   5: C+=acc   6: atomicAdd(C,acc)
// ---------------------------------------------------------------------------
#define BM 128
#define BN 64
#define BK 16
#define AS_STR 132
#define BS_STR 68

template<int TB, int EPI>
__global__ __launch_bounds__(256)
void gemm_k(const float* __restrict__ A, const float* __restrict__ B, float* __restrict__ C,
            int Mm, int Nn, int Kk, int lda, int ldb, int ldc,
            ll sA, ll sB, ll sC,
            const float* __restrict__ bias, const float* __restrict__ addp, int ldadd,
            float alpha, float diagv, int aRowOff, int aMaxRow, int ksplit)
{
    __shared__ float As[BK][AS_STR];
    __shared__ float Bs[BK][BS_STR];

    int bz = blockIdx.z;
    int batch = bz / ksplit;
    int kz = bz - batch * ksplit;
    A += (ll)batch * sA; B += (ll)batch * sB; C += (ll)batch * sC;

    int kTiles = Kk / BK;
    int tilesPer = (kTiles + ksplit - 1) / ksplit;
    int kt0 = kz * tilesPer;
    int kt1 = kt0 + tilesPer; if (kt1 > kTiles) kt1 = kTiles;

    int m0 = blockIdx.y * BM;
    int n0 = blockIdx.x * BN;
    int tid = threadIdx.x;
    int tx = tid & 15, ty = tid >> 4;

    // A load: 1 row per 2 threads, each thread 8 consecutive k's (2x float4)
    int arow_t = tid >> 1;
    int akh = (tid & 1) * 8;
    int arow_g = m0 + arow_t + aRowOff;
    bool avalid = (m0 + arow_t < Mm) && (arow_g >= 0) && (arow_g < aMaxRow);
    const float* Arow = A + (ll)arow_g * lda;

    float acc[8][4];
#pragma unroll
    for (int i = 0; i < 8; i++)
#pragma unroll
        for (int j = 0; j < 4; j++) acc[i][j] = 0.f;

    for (int kt = kt0; kt < kt1; ++kt) {
        int k0 = kt * BK;
        float4 av0 = make_float4(0.f, 0.f, 0.f, 0.f), av1 = av0;
        if (avalid) {
            av0 = *(const float4*)(Arow + k0 + akh);
            av1 = *(const float4*)(Arow + k0 + akh + 4);
        }
        float4 bv;
        if (TB == 0) {
            bv = *(const float4*)(B + (ll)(k0 + (tid >> 4)) * ldb + n0 + (tid & 15) * 4);
        } else {
            bv = *(const float4*)(B + (ll)(n0 + (tid >> 2)) * ldb + k0 + (tid & 3) * 4);
        }
        __syncthreads();
        As[akh + 0][arow_t] = av0.x; As[akh + 1][arow_t] = av0.y;
        As[akh + 2][arow_t] = av0.z; As[akh + 3][arow_t] = av0.w;
        As[akh + 4][arow_t] = av1.x; As[akh + 5][arow_t] = av1.y;
        As[akh + 6][arow_t] = av1.z; As[akh + 7][arow_t] = av1.w;
        if (TB == 0) {
            *(float4*)&Bs[tid >> 4][(tid & 15) * 4] = bv;
        } else {
            int bk4 = (tid & 3) * 4, bn = tid >> 2;
            Bs[bk4 + 0][bn] = bv.x; Bs[bk4 + 1][bn] = bv.y;
            Bs[bk4 + 2][bn] = bv.z; Bs[bk4 + 3][bn] = bv.w;
        }
        __syncthreads();
#pragma unroll
        for (int kk = 0; kk < BK; kk++) {
            float ar[8], br[4];
            *(float4*)&ar[0] = *(const float4*)&As[kk][ty * 8];
            *(float4*)&ar[4] = *(const float4*)&As[kk][ty * 8 + 4];
            *(float4*)&br[0] = *(const float4*)&Bs[kk][tx * 4];
#pragma unroll
            for (int i = 0; i < 8; i++)
#pragma unroll
                for (int j = 0; j < 4; j++)
                    acc[i][j] = fmaf(ar[i], br[j], acc[i][j]);
        }
    }

    int c0 = n0 + tx * 4;
#pragma unroll
    for (int i = 0; i < 8; i++) {
        int r = m0 + ty * 8 + i;
        if (r >= Mm) continue;
#pragma unroll
        for (int j = 0; j < 4; j++) {
            int c = c0 + j;
            if (c >= Nn) continue;
            float v = acc[i][j];
            if (EPI == 0) C[(ll)r * ldc + c] = alpha * v;
            else if (EPI == 1) C[(ll)r * ldc + c] = v + bias[c];
            else if (EPI == 2) C[(ll)r * ldc + c] = v + bias[c] + addp[(ll)r * ldadd + c];
            else if (EPI == 3) {
                int part = c >> 9, h = (c >> 6) & 7, dd = c & 63;
                float sc = (part == 0) ? 0.125f : 1.0f;   // q *= DIM_HEAD^-0.5
                C[((ll)(part * NHEAD + h) * Mm + r) * DHEAD + dd] = v * sc;
            }
            else if (EPI == 4) C[(ll)r * ldc + c] = ((r == c) ? diagv : 0.f) - v;
            else if (EPI == 5) C[(ll)r * ldc + c] += v;
            else if (EPI == 6) atomicAdd(&C[(ll)r * ldc + c], v);
        }
    }
}

// ---------------------------------------------------------------------------
// landmark means: dst[h][jm][d] = mean over 118 contiguous rows of src[h]
__global__ void landmark_mean(const float* __restrict__ src, float* __restrict__ dst)
{
    int b = blockIdx.x;            // h*256 + jm
    int h = b >> 8, jm = b & 255;
    int d = threadIdx.x;
    const float* p = src + ((ll)h * NPAD + (ll)jm * LCHUNK) * DHEAD + d;
    float s = 0.f;
    for (int jl = 0; jl < LCHUNK; ++jl) s += p[jl * DHEAD];
    dst[((h << 8) + jm) * DHEAD + d] = s * (1.0f / LCHUNK);
}

// exact softmax of a contiguous 256-wide row, in place
__global__ void rowsoftmax256(float* __restrict__ X)
{
    __shared__ float red[256];
    float* p = X + (ll)blockIdx.x * 256;
    int t = threadIdx.x;
    float v = p[t];
    red[t] = v; __syncthreads();
    for (int s = 128; s > 0; s >>= 1) { if (t < s) red[t] = fmaxf(red[t], red[t + s]); __syncthreads(); }
    float m = red[0]; __syncthreads();
    float e = expf(v - m);
    red[t] = e; __syncthreads();
    for (int s = 128; s > 0; s >>= 1) { if (t < s) red[t] += red[t + s]; __syncthreads(); }
    p[t] = e / red[0];
}

// streaming row softmax (unnormalized exp written back, rowsum stored)
__global__ void rowsoftmax_stream(float* __restrict__ X, float* __restrict__ rowsum, int len)
{
    __shared__ float red[256];
    float* p = X + (ll)blockIdx.x * len;
    int t = threadIdx.x;
    float m = -3.0e38f;
    for (int j = t; j < len; j += 256) m = fmaxf(m, p[j]);
    red[t] = m; __syncthreads();
    for (int s = 128; s > 0; s >>= 1) { if (t < s) red[t] = fmaxf(red[t], red[t + s]); __syncthreads(); }
    m = red[0]; __syncthreads();
    float sum = 0.f;
    for (int j = t; j < len; j += 256) { float e = expf(p[j] - m); p[j] = e; sum += e; }
    red[t] = sum; __syncthreads();
    for (int s = 128; s > 0; s >>= 1) { if (t < s) red[t] += red[t + s]; __syncthreads(); }
    if (t == 0) rowsum[blockIdx.x] = red[0];
}

// per-head max column-sum and max row-sum of softmaxed attn2
__global__ void colrow_max(const float* __restrict__ A2, float* __restrict__ hm)
{
    __shared__ float red[256];
    int h = blockIdx.x, t = threadIdx.x;
    const float* X = A2 + (ll)h * LM * LM;
    float cs = 0.f;
    for (int i = 0; i < LM; ++i) cs += X[i * LM + t];
    red[t] = cs; __syncthreads();
    for (int s = 128; s > 0; s >>= 1) { if (t < s) red[t] = fmaxf(red[t], red[t + s]); __syncthreads(); }
    if (t == 0) hm[h] = red[0];
    __syncthreads();
    float rs = 0.f;
    const float* Xr = X + (ll)t * LM;
    for (int j = 0; j < LM; ++j) rs += Xr[j];
    red[t] = rs; __syncthreads();
    for (int s = 128; s > 0; s >>= 1) { if (t < s) red[t] = fmaxf(red[t], red[t + s]); __syncthreads(); }
    if (t == 0) hm[8 + h] = red[0];
}

__global__ void denom_fin(const float* __restrict__ hm, float* __restrict__ scal)
{
    float cm = hm[0], rm = hm[8];
    for (int h = 1; h < 8; ++h) { cm = fmaxf(cm, hm[h]); rm = fmaxf(rm, hm[8 + h]); }
    scal[0] = 1.0f / (cm * rm);
}

// Z = A2^T / denom (per head)
__global__ void transpose_scale(const float* __restrict__ A2, float* __restrict__ Z,
                                const float* __restrict__ scal)
{
    ll e = (ll)blockIdx.x * 256 + threadIdx.x;   // < 8*65536
    int h = (int)(e >> 16); int r = (int)(e >> 8) & 255; int c = (int)e & 255;
    Z[e] = A2[((ll)h << 16) + ((ll)c << 8) + r] * scal[0];
}

// W = 7I - XZ
__global__ void seven_i_minus(const float* __restrict__ XZ, float* __restrict__ Wo)
{
    ll e = (ll)blockIdx.x * 256 + threadIdx.x;
    int r = (int)(e >> 8) & 255; int c = (int)e & 255;
    Wo[e] = ((r == c) ? 7.0f : 0.0f) - XZ[e];
}

__global__ void kv_div(const float* __restrict__ KVR, const float* __restrict__ RS,
                       float* __restrict__ KV)
{
    int e = blockIdx.x * 256 + threadIdx.x;   // < 8*256*64
    KV[e] = KVR[e] / RS[e >> 6];
}

// depthwise conv residual along sequence: ATT[i][h*64+d] = sum_k w[h][k]*V[h][FPAD+i+k-16][d]
__global__ void conv_res(const float* __restrict__ V, const float* __restrict__ cw,
                         float* __restrict__ ATT)
{
    int h = blockIdx.y;
    int i = blockIdx.x * 4 + (threadIdx.x >> 6);
    int d = threadIdx.x & 63;
    if (i >= NSEQ) return;
    const float* Vh = V + (ll)h * NPAD * DHEAD;
    int n0 = FPAD + i - 16;   // always >= 192
    float s = 0.f;
#pragma unroll
    for (int kk = 0; kk < 33; ++kk) {
        int n = n0 + kk;
        if (n < NPAD) s += cw[h * 33 + kk] * Vh[(ll)n * DHEAD + d];
    }
    ATT[(ll)i * INNER + h * DHEAD + d] = s;
}

__global__ void zero_f32(float* __restrict__ p, int n)
{
    int i = blockIdx.x * 256 + threadIdx.x;
    if (i < n) p[i] = 0.f;
}

// per-edge scores + segment sum (one wave per edge)
__global__ void edge_scores(const int* __restrict__ ei, const float* __restrict__ adj,
                            const float* __restrict__ q2, const float* __restrict__ k2,
                            float* __restrict__ Araw, int E)
{
    int gw = (blockIdx.x * 256 + threadIdx.x) >> 6;
    int lane = threadIdx.x & 63;
    if (gw >= E) return;
    int src = ei[gw], dst = ei[E + gw];
    const float* qp = q2 + (ll)src * 256;
    const float* kp = k2 + (ll)dst * 256;
    float acc = qp[lane] * kp[lane] + qp[lane + 64] * kp[lane + 64]
              + qp[lane + 128] * kp[lane + 128] + qp[lane + 192] * kp[lane + 192];
#pragma unroll
    for (int m = 32; m >= 1; m >>= 1) acc += __shfl_xor(acc, m, 64);
    if (lane == 0) atomicAdd(Araw + src, acc * adj[gw] * 0.0625f);   // 1/sqrt(256)
}

// global softmax stats over 30000 values (single block)
__global__ void softmax30k_stats(const float* __restrict__ A, float* __restrict__ scal)
{
    __shared__ float red[1024];
    int t = threadIdx.x;
    float m = -3.0e38f;
    for (int i = t; i < NSEQ; i += 1024) m = fmaxf(m, A[i]);
    red[t] = m; __syncthreads();
    for (int s = 512; s > 0; s >>= 1) { if (t < s) red[t] = fmaxf(red[t], red[t + s]); __syncthreads(); }
    m = red[0]; __syncthreads();
    float sum = 0.f;
    for (int i = t; i < NSEQ; i += 1024) sum += expf(A[i] - m);
    red[t] = sum; __syncthreads();
    for (int s = 512; s > 0; s >>= 1) { if (t < s) red[t] += red[t + s]; __syncthreads(); }
    if (t == 0) { scal[1] = m; scal[2] = red[0]; }
}

__global__ void alpha_kernel(const float* __restrict__ A, const float* __restrict__ scal,
                             float* __restrict__ alpha)
{
    int i = blockIdx.x * 256 + threadIdx.x;
    if (i < NSEQ) alpha[i] = expf(A[i] - scal[1]) / scal[2];
}

// xo = xl*2*sw + 2*enc*(1-sw), sw = sigmoid(-xl)^2, xl = alpha[i]*value
// (enc lives in the same buffer as out: elementwise read-then-write is safe)
__global__ void final_kernel(const float* __restrict__ alpha, const float* __restrict__ val,
                             const float* __restrict__ enc, float* __restrict__ out)
{
    ll e = (ll)blockIdx.x * 256 + threadIdx.x;
    int i = (int)(e >> 10);
    float xl = alpha[i] * val[e];
    float sg = 1.0f / (1.0f + expf(xl));   // sigmoid(-xl)
    float sw = sg * sg;
    out[e] = xl * 2.0f * sw + 2.0f * enc[e] * (1.0f - sw);
}

// ---------------------------------------------------------------------------
extern "C" void kernel_launch(void* const* d_in, const int* in_sizes, int n_in,
                              void* d_out, int out_size, void* d_ws, size_t ws_size,
                              hipStream_t stream)
{
    const float* dense  = (const float*)d_in[0];
    const int*   ei     = (const int*)d_in[1];
    const float* adj    = (const float*)d_in[2];
    const float* qkv_w  = (const float*)d_in[3];
    const float* out_w  = (const float*)d_in[4];
    const float* out_b  = (const float*)d_in[5];
    const float* conv_w = (const float*)d_in[6];
    const float* wq_w   = (const float*)d_in[7];
    const float* wq_b   = (const float*)d_in[8];
    const float* wk_w   = (const float*)d_in[9];
    const float* wk_b   = (const float*)d_in[10];
    const float* wv_w   = (const float*)d_in[11];
    const float* wv_b   = (const float*)d_in[12];
    int E = in_sizes[2];

    // workspace layout (fp32 elems); peak ~293 MB. ENC lives in d_out.
    float* W = (float*)d_ws;
    const ll HNP = (ll)NHEAD * NPAD * DHEAD;          // 15,466,496
    float* Qb  = W;
    float* Kb  = W + HNP;
    float* Vb  = W + 2 * HNP;
    float* ATT = W + 3 * HNP;                         // NSEQ*INNER
    float* LB  = ATT + (ll)NSEQ * INNER;              // LM*NPAD scratch
    float* QL  = LB + (ll)LM * NPAD;
    float* KL  = QL + LM * DHEAD * NHEAD;
    float* A2  = KL + LM * DHEAD * NHEAD;
    float* Zb  = A2 + (ll)NHEAD * LM * LM;
    float* Z2  = Zb + (ll)NHEAD * LM * LM;
    float* XZ  = Z2 + (ll)NHEAD * LM * LM;
    float* Wa  = XZ + (ll)NHEAD * LM * LM;
    float* Wb  = Wa + (ll)NHEAD * LM * LM;
    float* KVR = Wb + (ll)NHEAD * LM * LM;            // 131072
    float* KV  = KVR + 131072;
    float* PW  = KV + 131072;
    float* RS  = PW + 131072;                         // 2048
    float* HM  = RS + 2048;                           // 16
    float* SC  = HM + 64;                             // scalars
    float* ALPHA = SC + 64;                           // 30000

    float* OUT  = (float*)d_out;
    float* ENC  = OUT;                                // encoder_output staged in out
    float* ARAW = OUT + (ll)NSEQ * DMODEL;
    // late-phase reuse
    float* Q2  = LB;        // 30000*256
    float* K2  = Qb;        // 30000*256
    float* VAL = Kb;        // 30000*1024 (spans Kb+Vb)

#define G(TB, EPI, A_, B_, C_, M_, N_, K_, lda_, ldb_, ldc_, sA_, sB_, sC_, batch_, bias_, add_, ldadd_, alpha_, diagv_, aoff_, amax_, ksp_) \
    gemm_k<TB, EPI><<<dim3(((N_) + BN - 1) / BN, ((M_) + BM - 1) / BM, (batch_) * (ksp_)), 256, 0, stream>>>( \
        A_, B_, C_, M_, N_, K_, lda_, ldb_, ldc_, (ll)(sA_), (ll)(sB_), (ll)(sC_), bias_, add_, ldadd_, alpha_, diagv_, aoff_, amax_, ksp_)

    // 1) QKV projection (front-padded rows read as zero), scatter to per-head layout
    G(0, 3, dense, qkv_w, Qb, NPAD, 3 * INNER, DMODEL, DMODEL, 3 * INNER, 0, 0, 0, 0, 1,
      nullptr, nullptr, 0, 1.f, 0.f, -FPAD, NSEQ, 1);

    // 2) landmarks
    landmark_mean<<<NHEAD * LM, 64, 0, stream>>>(Qb, QL);
    landmark_mean<<<NHEAD * LM, 64, 0, stream>>>(Kb, KL);

    // 3) attn2 = softmax(QL @ KL^T)
    G(1, 0, QL, KL, A2, LM, LM, DHEAD, DHEAD, DHEAD, LM, LM * DHEAD, LM * DHEAD, LM * LM, NHEAD,
      nullptr, nullptr, 0, 1.f, 0.f, 0, LM, 1);
    rowsoftmax256<<<NHEAD * LM, 256, 0, stream>>>(A2);

    // 4) pinv denom + initial Z = attn2^T / denom
    colrow_max<<<NHEAD, 256, 0, stream>>>(A2, HM);
    denom_fin<<<1, 1, 0, stream>>>(HM, SC);
    transpose_scale<<<2048, 256, 0, stream>>>(A2, Zb, SC);

    // 5) 6 Moore-Penrose iterations (batched over heads)
    float* zc = Zb; float* zn = Z2;
    for (int it = 0; it < 6; ++it) {
        G(0, 0, A2, zc, XZ, LM, LM, LM, LM, LM, LM, LM * LM, LM * LM, LM * LM, NHEAD,
          nullptr, nullptr, 0, 1.f, 0.f, 0, LM, 1);
        seven_i_minus<<<2048, 256, 0, stream>>>(XZ, Wa);
        G(0, 4, XZ, Wa, Wb, LM, LM, LM, LM, LM, LM, LM * LM, LM * LM, LM * LM, NHEAD,
          nullptr, nullptr, 0, 1.f, 15.f, 0, LM, 1);
        G(0, 4, XZ, Wb, Wa, LM, LM, LM, LM, LM, LM, LM * LM, LM * LM, LM * LM, NHEAD,
          nullptr, nullptr, 0, 1.f, 13.f, 0, LM, 1);
        G(0, 0, zc, Wa, zn, LM, LM, LM, LM, LM, LM, LM * LM, LM * LM, LM * LM, NHEAD,
          nullptr, nullptr, 0, 0.25f, 0.f, 0, LM, 1);
        float* t = zc; zc = zn; zn = t;
    }
    // zc == pinv(attn2)

    // 6) attn3 = softmax(QL @ K^T); KV = attn3 @ V (per head; split-K PV)
    zero_f32<<<(131072 + 255) / 256, 256, 0, stream>>>(KVR, 131072);
    for (int h = 0; h < NHEAD; ++h) {
        G(1, 0, QL + (ll)h * LM * DHEAD, Kb + (ll)h * NPAD * DHEAD, LB,
          LM, NPAD, DHEAD, DHEAD, DHEAD, NPAD, 0, 0, 0, 1,
          nullptr, nullptr, 0, 1.f, 0.f, 0, LM, 1);
        rowsoftmax_stream<<<LM, 256, 0, stream>>>(LB, RS + h * LM, NPAD);
        G(0, 6, LB, Vb + (ll)h * NPAD * DHEAD, KVR + (ll)h * LM * DHEAD,
          LM, DHEAD, NPAD, NPAD, DHEAD, DHEAD, 0, 0, 0, 1,
          nullptr, nullptr, 0, 1.f, 0.f, 0, LM, 64);
    }
    kv_div<<<512, 256, 0, stream>>>(KVR, RS, KV);

    // 7) PW = pinv(attn2) @ KV  (reassociated: out = attn1 @ PW)
    G(0, 0, zc, KV, PW, LM, DHEAD, LM, LM, DHEAD, DHEAD, LM * LM, LM * DHEAD, LM * DHEAD, NHEAD,
      nullptr, nullptr, 0, 1.f, 0.f, 0, LM, 1);

    // 8) depthwise conv residual -> ATT
    conv_res<<<dim3((NSEQ + 3) / 4, NHEAD), 256, 0, stream>>>(Vb, conv_w, ATT);

    // 9) attn1 = softmax(Q @ KL^T); ATT += attn1 @ PW (per head; only unpadded rows)
    for (int h = 0; h < NHEAD; ++h) {
        G(1, 0, Qb + (ll)h * NPAD * DHEAD, KL + (ll)h * LM * DHEAD, LB,
          NSEQ, LM, DHEAD, DHEAD, DHEAD, LM, 0, 0, 0, 1,
          nullptr, nullptr, 0, 1.f, 0.f, FPAD, NPAD, 1);
        rowsoftmax256<<<NSEQ, 256, 0, stream>>>(LB);
        G(0, 5, LB, PW + (ll)h * LM * DHEAD, ATT + h * DHEAD,
          NSEQ, DHEAD, LM, LM, DHEAD, INNER, 0, 0, 0, 1,
          nullptr, nullptr, 0, 1.f, 0.f, 0, NSEQ, 1);
    }

    // 10) out projection + out_b + dense residual -> ENC (in d_out)
    G(0, 2, ATT, out_w, ENC, NSEQ, DMODEL, INNER, INNER, DMODEL, DMODEL, 0, 0, 0, 1,
      out_b, dense, DMODEL, 1.f, 0.f, 0, NSEQ, 1);

    // 11) q2 / k2 projections
    G(0, 1, ENC, wq_w, Q2, NSEQ, 256, DMODEL, DMODEL, 256, 256, 0, 0, 0, 1,
      wq_b, nullptr, 0, 1.f, 0.f, 0, NSEQ, 1);
    G(0, 1, ENC, wk_w, K2, NSEQ, 256, DMODEL, DMODEL, 256, 256, 0, 0, 0, 1,
      wk_b, nullptr, 0, 1.f, 0.f, 0, NSEQ, 1);

    // 12) per-edge scores -> segment sum into A_raw (in d_out)
    zero_f32<<<(NSEQ + 255) / 256, 256, 0, stream>>>(ARAW, NSEQ);
    edge_scores<<<(E + 3) / 4, 256, 0, stream>>>(ei, adj, Q2, K2, ARAW, E);

    // 13) global softmax of A_raw -> alpha
    softmax30k_stats<<<1, 1024, 0, stream>>>(ARAW, SC);
    alpha_kernel<<<(NSEQ + 255) / 256, 256, 0, stream>>>(ARAW, SC, ALPHA);

    // 14) value = dense @ wv_w + wv_b
    G(0, 1, dense, wv_w, VAL, NSEQ, DMODEL, DMODEL, DMODEL, DMODEL, DMODEL, 0, 0, 0, 1,
      wv_b, nullptr, 0, 1.f, 0.f, 0, NSEQ, 1);

    // 15) final gating -> xo (overwrites ENC in place, elementwise)
    final_kernel<<<(int)(((ll)NSEQ * DMODEL) / 256), 256, 0, stream>>>(ALPHA, VAL, ENC, OUT);

#undef G
}

// Round 2
// 2456.972 us; speedup vs baseline: 2.4713x; 2.4713x over previous
//
#include <hip/hip_runtime.h>

#define NSEQ   30000
#define NPAD   30208
#define FPAD   208
#define DMODEL 1024
#define NHEAD  8
#define DHEAD  64
#define LM     256
#define LCHUNK 118
#define INNER  512

typedef long long ll;
typedef __attribute__((ext_vector_type(8))) __bf16 bf16x8;
typedef __attribute__((ext_vector_type(4))) float f32x4;

__device__ __forceinline__ float b2f(unsigned short u) {
    union { unsigned int i; float f; } x; x.i = ((unsigned int)u) << 16; return x.f;
}
__device__ __forceinline__ unsigned short f2b(float f) {
    union { float f; unsigned int i; } x; x.f = f;
    unsigned int r = x.i + 0x7fffu + ((x.i >> 16) & 1u);
    return (unsigned short)(r >> 16);
}
__device__ __forceinline__ void gload16(const unsigned short* g, unsigned short* l) {
    __builtin_amdgcn_global_load_lds(
        (__attribute__((address_space(1))) void*)(const_cast<unsigned short*>(g)),
        (__attribute__((address_space(3))) void*)l, 16, 0, 0);
}

// ---------------------------------------------------------------------------
// bf16 MFMA GEMM: C = A(MxK) @ Bt(NxK)^T. 128x128 tile, BK=32, 256 thr (4 waves,
// 2x2 of 64x64), 16x16x32 MFMA, global_load_lds(16B) staging with chunk-XOR
// swizzle (chunk c at LDS pos c ^ ((row>>1)&3)); frag reads apply same XOR.
// EPI: 0 C=acc  1 C=acc+bias[c] (store at r-rSub)  2 C=acc+bias+addp[r], C2=bf16
//      3 QKV scatter -> C2[(part*8+h)*NPAD..] bf16, q*0.125
//      4 C2 = bf16(acc)  5 C[kz part] = acc  6 C += acc (store at r-rSub)
// ---------------------------------------------------------------------------
template<int EPI>
__global__ __launch_bounds__(256)
void bgemm(const unsigned short* __restrict__ A, const unsigned short* __restrict__ Bt,
           float* __restrict__ C, unsigned short* __restrict__ C2,
           const float* __restrict__ bias, const float* __restrict__ addp,
           int Mm, int Nn, int Kk, int lda, int ldb, int ldc, int ldadd,
           ll sA, ll sB, ll sC, ll sKz, int ksplit,
           int Mstore, int Nstore, int rSub)
{
    __shared__ unsigned short As[128 * 32];
    __shared__ unsigned short Bs[128 * 32];

    int bz = blockIdx.z;
    int batch = bz / ksplit, kz = bz - batch * ksplit;
    A  += (ll)batch * sA;
    Bt += (ll)batch * sB;
    ll cOff = (ll)batch * sC + (ll)kz * sKz;

    int m0 = blockIdx.y * 128, n0 = blockIdx.x * 128;
    int tid = threadIdx.x, w = tid >> 6, lane = tid & 63;
    int wr = w >> 1, wc = w & 1;

    int ktot = Kk >> 5;
    int per = (ktot + ksplit - 1) / ksplit;
    int kt0 = kz * per, kt1 = kt0 + per; if (kt1 > ktot) kt1 = ktot;

    // staging: wave w owns chunks [w*128, w*128+128), 2 groups of 64 (1/lane)
    int q0 = w * 128;
    int qa0 = q0 + lane, qa1 = q0 + 64 + lane;
    int r0s = qa0 >> 2, c0s = (qa0 & 3) ^ ((r0s >> 1) & 3);
    int r1s = qa1 >> 2, c1s = (qa1 & 3) ^ ((r1s >> 1) & 3);
    int ar0 = m0 + r0s; if (ar0 > Mm - 1) ar0 = Mm - 1;
    int ar1 = m0 + r1s; if (ar1 > Mm - 1) ar1 = Mm - 1;
    int br0 = n0 + r0s; if (br0 > Nn - 1) br0 = Nn - 1;
    int br1 = n0 + r1s; if (br1 > Nn - 1) br1 = Nn - 1;
    const unsigned short* pa0 = A + (ll)ar0 * lda + c0s * 8;
    const unsigned short* pa1 = A + (ll)ar1 * lda + c1s * 8;
    const unsigned short* pb0 = Bt + (ll)br0 * ldb + c0s * 8;
    const unsigned short* pb1 = Bt + (ll)br1 * ldb + c1s * 8;
    unsigned short* la0 = &As[q0 * 8];
    unsigned short* la1 = &As[(q0 + 64) * 8];
    unsigned short* lb0 = &Bs[q0 * 8];
    unsigned short* lb1 = &Bs[(q0 + 64) * 8];

    int l15 = lane & 15, l4 = lane >> 4;
    int aoff[4], boff[4];
#pragma unroll
    for (int f = 0; f < 4; f++) {
        int row = wr * 64 + f * 16 + l15;
        aoff[f] = row * 32 + ((l4 ^ ((row >> 1) & 3)) << 3);
        int col = wc * 64 + f * 16 + l15;
        boff[f] = col * 32 + ((l4 ^ ((col >> 1) & 3)) << 3);
    }

    f32x4 acc[4][4];
#pragma unroll
    for (int i = 0; i < 4; i++)
#pragma unroll
        for (int j = 0; j < 4; j++) acc[i][j] = (f32x4){0.f, 0.f, 0.f, 0.f};

    for (int kt = kt0; kt < kt1; ++kt) {
        int k0 = kt << 5;
        gload16(pa0 + k0, la0);
        gload16(pa1 + k0, la1);
        gload16(pb0 + k0, lb0);
        gload16(pb1 + k0, lb1);
        __syncthreads();
        bf16x8 af[4], bfr[4];
#pragma unroll
        for (int f = 0; f < 4; f++) af[f] = *(const bf16x8*)&As[aoff[f]];
#pragma unroll
        for (int f = 0; f < 4; f++) bfr[f] = *(const bf16x8*)&Bs[boff[f]];
#pragma unroll
        for (int i = 0; i < 4; i++)
#pragma unroll
            for (int j = 0; j < 4; j++)
                acc[i][j] = __builtin_amdgcn_mfma_f32_16x16x32_bf16(af[i], bfr[j], acc[i][j], 0, 0, 0);
        __syncthreads();
    }

#pragma unroll
    for (int fm = 0; fm < 4; fm++) {
        int rb = m0 + wr * 64 + fm * 16 + l4 * 4;
#pragma unroll
        for (int fn = 0; fn < 4; fn++) {
            int c = n0 + wc * 64 + fn * 16 + l15;
            if (c >= Nstore) continue;
#pragma unroll
            for (int i = 0; i < 4; i++) {
                int r = rb + i - rSub;
                if (r < 0 || r >= Mstore) continue;
                float v = acc[fm][fn][i];
                if (EPI == 0) C[cOff + (ll)r * ldc + c] = v;
                else if (EPI == 1) C[cOff + (ll)r * ldc + c] = v + bias[c];
                else if (EPI == 2) {
                    float o = v + bias[c] + addp[(ll)r * ldadd + c];
                    C[(ll)r * ldc + c] = o;
                    C2[(ll)r * ldc + c] = f2b(o);
                } else if (EPI == 3) {
                    int part = c >> 9, h = (c >> 6) & 7, dd = c & 63;
                    float o = (part == 0) ? v * 0.125f : v;
                    C2[((ll)(part * 8 + h) * NPAD + r) * 64 + dd] = f2b(o);
                } else if (EPI == 4) C2[cOff + (ll)r * ldc + c] = f2b(v);
                else if (EPI == 5) C[cOff + (ll)r * ldc + c] = v;
                else if (EPI == 6) C[cOff + (ll)r * ldc + c] += v;
            }
        }
    }
}

// ---------------------------------------------------------------------------
// fp32 GEMM for the pinv / attn2 chain (small, precision-critical).
#define BM 128
#define BN 64
#define BK 16
template<int TB, int EPI>
__global__ __launch_bounds__(256)
void gemm_k(const float* __restrict__ A, const float* __restrict__ B, float* __restrict__ C,
            int Mm, int Nn, int Kk, int lda, int ldb, int ldc,
            ll sA, ll sB, ll sC, float alpha, float diagv)
{
    __shared__ float As[BK][132];
    __shared__ float Bs[BK][68];
    int batch = blockIdx.z;
    A += (ll)batch * sA; B += (ll)batch * sB; C += (ll)batch * sC;
    int m0 = blockIdx.y * BM, n0 = blockIdx.x * BN;
    int tid = threadIdx.x, tx = tid & 15, ty = tid >> 4;
    int arow_t = tid >> 1, akh = (tid & 1) * 8;
    bool avalid = (m0 + arow_t < Mm);
    const float* Arow = A + (ll)(m0 + arow_t) * lda;
    float acc[8][4];
#pragma unroll
    for (int i = 0; i < 8; i++)
#pragma unroll
        for (int j = 0; j < 4; j++) acc[i][j] = 0.f;
    for (int kt = 0; kt < Kk / BK; ++kt) {
        int k0 = kt * BK;
        float4 av0 = make_float4(0, 0, 0, 0), av1 = av0;
        if (avalid) {
            av0 = *(const float4*)(Arow + k0 + akh);
            av1 = *(const float4*)(Arow + k0 + akh + 4);
        }
        float4 bv;
        if (TB == 0) bv = *(const float4*)(B + (ll)(k0 + (tid >> 4)) * ldb + n0 + (tid & 15) * 4);
        else         bv = *(const float4*)(B + (ll)(n0 + (tid >> 2)) * ldb + k0 + (tid & 3) * 4);
        __syncthreads();
        As[akh + 0][arow_t] = av0.x; As[akh + 1][arow_t] = av0.y;
        As[akh + 2][arow_t] = av0.z; As[akh + 3][arow_t] = av0.w;
        As[akh + 4][arow_t] = av1.x; As[akh + 5][arow_t] = av1.y;
        As[akh + 6][arow_t] = av1.z; As[akh + 7][arow_t] = av1.w;
        if (TB == 0) *(float4*)&Bs[tid >> 4][(tid & 15) * 4] = bv;
        else {
            int bk4 = (tid & 3) * 4, bn = tid >> 2;
            Bs[bk4 + 0][bn] = bv.x; Bs[bk4 + 1][bn] = bv.y;
            Bs[bk4 + 2][bn] = bv.z; Bs[bk4 + 3][bn] = bv.w;
        }
        __syncthreads();
#pragma unroll
        for (int kk = 0; kk < BK; kk++) {
            float ar[8], br[4];
            *(float4*)&ar[0] = *(const float4*)&As[kk][ty * 8];
            *(float4*)&ar[4] = *(const float4*)&As[kk][ty * 8 + 4];
            *(float4*)&br[0] = *(const float4*)&Bs[kk][tx * 4];
#pragma unroll
            for (int i = 0; i < 8; i++)
#pragma unroll
                for (int j = 0; j < 4; j++) acc[i][j] = fmaf(ar[i], br[j], acc[i][j]);
        }
    }
    int c0 = n0 + tx * 4;
#pragma unroll
    for (int i = 0; i < 8; i++) {
        int r = m0 + ty * 8 + i;
        if (r >= Mm) continue;
#pragma unroll
        for (int j = 0; j < 4; j++) {
            int c = c0 + j;
            if (c >= Nn) continue;
            float v = acc[i][j];
            if (EPI == 0) C[(ll)r * ldc + c] = alpha * v;
            else if (EPI == 4) C[(ll)r * ldc + c] = ((r == c) ? diagv : 0.f) - v;
        }
    }
}

// ---------------------------------------------------------------------------
__global__ void trans_f2b(const float* __restrict__ in, unsigned short* __restrict__ out,
                          int R, int Cc, ll sI, ll sO)
{
    __shared__ float tile[32][33];
    const float* inp = in + (ll)blockIdx.z * sI;
    unsigned short* outp = out + (ll)blockIdx.z * sO;
    int r0 = blockIdx.y * 32, c0 = blockIdx.x * 32;
    int tx = threadIdx.x & 31, ty = threadIdx.x >> 5;
#pragma unroll
    for (int i = 0; i < 4; i++) {
        int r = r0 + ty + i * 8, c = c0 + tx;
        tile[ty + i * 8][tx] = (r < R && c < Cc) ? inp[(ll)r * Cc + c] : 0.f;
    }
    __syncthreads();
#pragma unroll
    for (int i = 0; i < 4; i++) {
        int c = c0 + ty + i * 8, r = r0 + tx;
        if (c < Cc && r < R) outp[(ll)c * R + r] = f2b(tile[tx][ty + i * 8]);
    }
}

__global__ void trans_b2b(const unsigned short* __restrict__ in, unsigned short* __restrict__ out,
                          int R, int Cc, ll sI, ll sO)
{
    __shared__ unsigned short tile[32][34];
    const unsigned short* inp = in + (ll)blockIdx.z * sI;
    unsigned short* outp = out + (ll)blockIdx.z * sO;
    int r0 = blockIdx.y * 32, c0 = blockIdx.x * 32;
    int tx = threadIdx.x & 31, ty = threadIdx.x >> 5;
#pragma unroll
    for (int i = 0; i < 4; i++) {
        int r = r0 + ty + i * 8, c = c0 + tx;
        tile[ty + i * 8][tx] = (r < R && c < Cc) ? inp[(ll)r * Cc + c] : (unsigned short)0;
    }
    __syncthreads();
#pragma unroll
    for (int i = 0; i < 4; i++) {
        int c = c0 + ty + i * 8, r = r0 + tx;
        if (c < Cc && r < R) outp[(ll)c * R + r] = tile[tx][ty + i * 8];
    }
}

__global__ void dense_pad_b(const float* __restrict__ x, unsigned short* __restrict__ o)
{
    ll e4 = ((ll)blockIdx.x * 256 + threadIdx.x) * 4;
    int r = (int)(e4 >> 10), c = (int)(e4 & 1023);
    ushort4 u;
    if (r < FPAD) { u.x = u.y = u.z = u.w = 0; }
    else {
        float4 v = *(const float4*)&x[(ll)(r - FPAD) * 1024 + c];
        u.x = f2b(v.x); u.y = f2b(v.y); u.z = f2b(v.z); u.w = f2b(v.w);
    }
    *(ushort4*)&o[e4] = u;
}

__global__ void f2b_vec(const float* __restrict__ in, unsigned short* __restrict__ out, int n)
{
    int i = blockIdx.x * 256 + threadIdx.x;
    if (i < n) out[i] = f2b(in[i]);
}

__global__ void zero_b16(unsigned short* p, int n)
{
    int i = blockIdx.x * 256 + threadIdx.x;
    if (i < n) p[i] = 0;
}

__global__ void att2attp(const float* __restrict__ att, unsigned short* __restrict__ attp)
{
    ll e = (ll)blockIdx.x * 256 + threadIdx.x;   // < NPAD*512
    int r = (int)(e >> 9);
    attp[e] = (r < NSEQ) ? f2b(att[e]) : (unsigned short)0;
}

__global__ void landmark_mean_b(const unsigned short* __restrict__ src, float* __restrict__ dst)
{
    int b = blockIdx.x;            // h*256 + jm
    int h = b >> 8, jm = b & 255;
    int d = threadIdx.x;
    const unsigned short* p = src + ((ll)h * NPAD + (ll)jm * LCHUNK) * DHEAD + d;
    float s = 0.f;
    for (int jl = 0; jl < LCHUNK; ++jl) s += b2f(p[jl * DHEAD]);
    dst[((h << 8) + jm) * DHEAD + d] = s * (1.0f / LCHUNK);
}

__global__ void rowsoftmax256(float* __restrict__ X)
{
    __shared__ float red[256];
    float* p = X + (ll)blockIdx.x * 256;
    int t = threadIdx.x;
    float v = p[t];
    red[t] = v; __syncthreads();
    for (int s = 128; s > 0; s >>= 1) { if (t < s) red[t] = fmaxf(red[t], red[t + s]); __syncthreads(); }
    float m = red[0]; __syncthreads();
    float e = expf(v - m);
    red[t] = e; __syncthreads();
    for (int s = 128; s > 0; s >>= 1) { if (t < s) red[t] += red[t + s]; __syncthreads(); }
    p[t] = e / red[0];
}

__global__ void softmax256_b(unsigned short* __restrict__ P)
{
    __shared__ float red[256];
    unsigned short* p = P + (ll)blockIdx.x * 256;
    int t = threadIdx.x;
    float v = b2f(p[t]);
    red[t] = v; __syncthreads();
    for (int s = 128; s > 0; s >>= 1) { if (t < s) red[t] = fmaxf(red[t], red[t + s]); __syncthreads(); }
    float m = red[0]; __syncthreads();
    float e = expf(v - m);
    red[t] = e; __syncthreads();
    for (int s = 128; s > 0; s >>= 1) { if (t < s) red[t] += red[t + s]; __syncthreads(); }
    p[t] = f2b(e / red[0]);
}

__global__ void softmax_stream_b(unsigned short* __restrict__ X, float* __restrict__ rowsum)
{
    __shared__ float red[256];
    unsigned short* p = X + (ll)blockIdx.x * NPAD;
    int t = threadIdx.x;
    float m = -3.0e38f;
    for (int j = t; j < NPAD; j += 256) m = fmaxf(m, b2f(p[j]));
    red[t] = m; __syncthreads();
    for (int s = 128; s > 0; s >>= 1) { if (t < s) red[t] = fmaxf(red[t], red[t + s]); __syncthreads(); }
    m = red[0]; __syncthreads();
    float sum = 0.f;
    for (int j = t; j < NPAD; j += 256) { float e = expf(b2f(p[j]) - m); p[j] = f2b(e); sum += e; }
    red[t] = sum; __syncthreads();
    for (int s = 128; s > 0; s >>= 1) { if (t < s) red[t] += red[t + s]; __syncthreads(); }
    if (t == 0) rowsum[blockIdx.x] = red[0];
}

__global__ void colrow_max(const float* __restrict__ A2, float* __restrict__ hm)
{
    __shared__ float red[256];
    int h = blockIdx.x, t = threadIdx.x;
    const float* X = A2 + (ll)h * LM * LM;
    float cs = 0.f;
    for (int i = 0; i < LM; ++i) cs += X[i * LM + t];
    red[t] = cs; __syncthreads();
    for (int s = 128; s > 0; s >>= 1) { if (t < s) red[t] = fmaxf(red[t], red[t + s]); __syncthreads(); }
    if (t == 0) hm[h] = red[0];
    __syncthreads();
    float rs = 0.f;
    const float* Xr = X + (ll)t * LM;
    for (int j = 0; j < LM; ++j) rs += Xr[j];
    red[t] = rs; __syncthreads();
    for (int s = 128; s > 0; s >>= 1) { if (t < s) red[t] = fmaxf(red[t], red[t + s]); __syncthreads(); }
    if (t == 0) hm[8 + h] = red[0];
}

__global__ void denom_fin(const float* __restrict__ hm, float* __restrict__ scal)
{
    float cm = hm[0], rm = hm[8];
    for (int h = 1; h < 8; ++h) { cm = fmaxf(cm, hm[h]); rm = fmaxf(rm, hm[8 + h]); }
    scal[0] = 1.0f / (cm * rm);
}

__global__ void transpose_scale(const float* __restrict__ A2, float* __restrict__ Z,
                                const float* __restrict__ scal)
{
    ll e = (ll)blockIdx.x * 256 + threadIdx.x;
    int h = (int)(e >> 16); int r = (int)(e >> 8) & 255; int c = (int)e & 255;
    Z[e] = A2[((ll)h << 16) + ((ll)c << 8) + r] * scal[0];
}

__global__ void seven_i_minus(const float* __restrict__ XZ, float* __restrict__ Wo)
{
    ll e = (ll)blockIdx.x * 256 + threadIdx.x;
    int r = (int)(e >> 8) & 255; int c = (int)e & 255;
    Wo[e] = ((r == c) ? 7.0f : 0.0f) - XZ[e];
}

__global__ void kv_reduce(const float* __restrict__ KVP, const float* __restrict__ RS,
                          float* __restrict__ KV)
{
    int e = blockIdx.x * 256 + threadIdx.x;   // < 131072
    int h = e >> 14;
    float s = 0.f;
#pragma unroll
    for (int ks = 0; ks < 16; ++ks) s += KVP[(ll)h * 262144 + ks * 16384 + (e & 16383)];
    KV[e] = s / RS[e >> 6];
}

__global__ void conv_res(const unsigned short* __restrict__ V, const float* __restrict__ cw,
                         float* __restrict__ ATT)
{
    int h = blockIdx.y;
    int i = blockIdx.x * 4 + (threadIdx.x >> 6);
    int d = threadIdx.x & 63;
    if (i >= NSEQ) return;
    const unsigned short* Vh = V + (ll)h * NPAD * DHEAD;
    int n0 = FPAD + i - 16;
    float s = 0.f;
#pragma unroll
    for (int kk = 0; kk < 33; ++kk) {
        int n = n0 + kk;
        if (n < NPAD) s += cw[h * 33 + kk] * b2f(Vh[(ll)n * DHEAD + d]);
    }
    ATT[(ll)i * INNER + h * DHEAD + d] = s;
}

__global__ void zero_f32(float* __restrict__ p, int n)
{
    int i = blockIdx.x * 256 + threadIdx.x;
    if (i < n) p[i] = 0.f;
}

__global__ void edge_scores(const int* __restrict__ ei, const float* __restrict__ adj,
                            const float* __restrict__ q2, const float* __restrict__ k2,
                            float* __restrict__ Araw, int E)
{
    int gw = (blockIdx.x * 256 + threadIdx.x) >> 6;
    int lane = threadIdx.x & 63;
    if (gw >= E) return;
    int src = ei[gw], dst = ei[E + gw];
    const float* qp = q2 + (ll)src * 256;
    const float* kp = k2 + (ll)dst * 256;
    float acc = qp[lane] * kp[lane] + qp[lane + 64] * kp[lane + 64]
              + qp[lane + 128] * kp[lane + 128] + qp[lane + 192] * kp[lane + 192];
#pragma unroll
    for (int m = 32; m >= 1; m >>= 1) acc += __shfl_xor(acc, m, 64);
    if (lane == 0) atomicAdd(Araw + src, acc * adj[gw] * 0.0625f);
}

__global__ void softmax30k_stats(const float* __restrict__ A, float* __restrict__ scal)
{
    __shared__ float red[1024];
    int t = threadIdx.x;
    float m = -3.0e38f;
    for (int i = t; i < NSEQ; i += 1024) m = fmaxf(m, A[i]);
    red[t] = m; __syncthreads();
    for (int s = 512; s > 0; s >>= 1) { if (t < s) red[t] = fmaxf(red[t], red[t + s]); __syncthreads(); }
    m = red[0]; __syncthreads();
    float sum = 0.f;
    for (int i = t; i < NSEQ; i += 1024) sum += expf(A[i] - m);
    red[t] = sum; __syncthreads();
    for (int s = 512; s > 0; s >>= 1) { if (t < s) red[t] += red[t + s]; __syncthreads(); }
    if (t == 0) { scal[1] = m; scal[2] = red[0]; }
}

__global__ void alpha_kernel(const float* __restrict__ A, const float* __restrict__ scal,
                             float* __restrict__ alpha)
{
    int i = blockIdx.x * 256 + threadIdx.x;
    if (i < NSEQ) alpha[i] = expf(A[i] - scal[1]) / scal[2];
}

__global__ void final_kernel(const float* __restrict__ alpha, const float* __restrict__ val,
                             const float* __restrict__ enc, float* __restrict__ out)
{
    ll e = (ll)blockIdx.x * 256 + threadIdx.x;
    int i = (int)(e >> 10);
    float xl = alpha[i] * val[e];
    float sg = 1.0f / (1.0f + expf(xl));
    float sw = sg * sg;
    out[e] = xl * 2.0f * sw + 2.0f * enc[e] * (1.0f - sw);
}

// ---------------------------------------------------------------------------
extern "C" void kernel_launch(void* const* d_in, const int* in_sizes, int n_in,
                              void* d_out, int out_size, void* d_ws, size_t ws_size,
                              hipStream_t stream)
{
    const float* dense  = (const float*)d_in[0];
    const int*   ei     = (const int*)d_in[1];
    const float* adj    = (const float*)d_in[2];
    const float* qkv_w  = (const float*)d_in[3];
    const float* out_w  = (const float*)d_in[4];
    const float* out_b  = (const float*)d_in[5];
    const float* conv_w = (const float*)d_in[6];
    const float* wq_w   = (const float*)d_in[7];
    const float* wq_b   = (const float*)d_in[8];
    const float* wk_w   = (const float*)d_in[9];
    const float* wk_b   = (const float*)d_in[10];
    const float* wv_w   = (const float*)d_in[11];
    const float* wv_b   = (const float*)d_in[12];
    int E = in_sizes[2];

    typedef unsigned short us;
    char* w = (char*)d_ws;
    auto alloc = [&](ll bytes) { char* p = w; w += (bytes + 255) & ~(ll)255; return p; };

    us*    DENSEP = (us*)alloc((ll)NPAD * 1024 * 2);
    us*    QKVH   = (us*)alloc((ll)3 * 8 * NPAD * 64 * 2);
    us*    ENCB   = QKVH;                         // alias: dead by the time ENCB lives
    us*    Qh = QKVH, *Kh = QKVH + (ll)8 * NPAD * 64, *Vh = QKVH + (ll)16 * NPAD * 64;
    us*    VT     = (us*)alloc((ll)8 * 64 * NPAD * 2);
    us*    QKVWT  = (us*)alloc((ll)1536 * 1024 * 2);
    us*    OUTWT  = (us*)alloc((ll)1024 * 512 * 2);
    us*    WQT    = (us*)alloc((ll)256 * 1024 * 2);
    us*    WKT    = (us*)alloc((ll)256 * 1024 * 2);
    us*    WVT    = (us*)alloc((ll)1024 * 1024 * 2);
    float* QL     = (float*)alloc((ll)8 * 256 * 64 * 4);
    float* KL     = (float*)alloc((ll)8 * 256 * 64 * 4);
    us*    QLB    = (us*)alloc((ll)8 * 256 * 64 * 2);
    us*    KLB    = (us*)alloc((ll)8 * 256 * 64 * 2);
    float* A2     = (float*)alloc((ll)8 * 65536 * 4);
    float* ZB     = (float*)alloc((ll)8 * 65536 * 4);
    float* Z2     = (float*)alloc((ll)8 * 65536 * 4);
    float* XZ     = (float*)alloc((ll)8 * 65536 * 4);
    float* WA     = (float*)alloc((ll)8 * 65536 * 4);
    float* WB     = (float*)alloc((ll)8 * 65536 * 4);
    float* KVP    = (float*)alloc((ll)8 * 16 * 16384 * 4);
    float* KV     = (float*)alloc((ll)8 * 16384 * 4);
    float* PW     = (float*)alloc((ll)8 * 16384 * 4);
    us*    PWT    = (us*)alloc((ll)8 * 16384 * 2);
    float* RS     = (float*)alloc(2048 * 4);
    float* HM     = (float*)alloc(64 * 4);
    float* SC     = (float*)alloc(64 * 4);
    float* ALPHA  = (float*)alloc(30000 * 4);
    us*    P1     = (us*)alloc((ll)2 * NPAD * 256 * 2);
    char*  BIG    = alloc((ll)8 * 256 * NPAD * 2);   // 123.7 MB, serially reused
    us*    P3   = (us*)BIG;
    float* ATT  = (float*)BIG;
    us*    ATTP = (us*)(BIG + (ll)NSEQ * 512 * 4);
    float* Q2   = (float*)BIG;
    float* K2   = (float*)(BIG + (ll)NSEQ * 256 * 4);
    float* VAL  = (float*)BIG;

    float* OUT  = (float*)d_out;
    float* ENC  = OUT;
    float* ARAW = OUT + (ll)NSEQ * DMODEL;

    // ---- prep: weight transposes + padded bf16 dense
    trans_f2b<<<dim3(48, 32, 1), 256, 0, stream>>>(qkv_w, QKVWT, 1024, 1536, 0, 0);
    trans_f2b<<<dim3(32, 16, 1), 256, 0, stream>>>(out_w, OUTWT, 512, 1024, 0, 0);
    trans_f2b<<<dim3(8, 32, 1), 256, 0, stream>>>(wq_w, WQT, 1024, 256, 0, 0);
    trans_f2b<<<dim3(8, 32, 1), 256, 0, stream>>>(wk_w, WKT, 1024, 256, 0, 0);
    trans_f2b<<<dim3(32, 32, 1), 256, 0, stream>>>(wv_w, WVT, 1024, 1024, 0, 0);
    dense_pad_b<<<NPAD, 256, 0, stream>>>(dense, DENSEP);

    // ---- QKV projection -> per-head bf16 Q,K,V (q pre-scaled by 1/8)
    bgemm<3><<<dim3(12, 236, 1), 256, 0, stream>>>(DENSEP, QKVWT, nullptr, QKVH,
        nullptr, nullptr, NPAD, 1536, 1024, 1024, 1024, 0, 0,
        0, 0, 0, 0, 1, NPAD, 1536, 0);

    // ---- landmarks (fp32 accumulate from bf16)
    landmark_mean_b<<<2048, 64, 0, stream>>>(Qh, QL);
    landmark_mean_b<<<2048, 64, 0, stream>>>(Kh, KL);
    f2b_vec<<<512, 256, 0, stream>>>(QL, QLB, 131072);
    f2b_vec<<<512, 256, 0, stream>>>(KL, KLB, 131072);

    // ---- attn2 + pinv (fp32 chain)
    gemm_k<1, 0><<<dim3(4, 2, 8), 256, 0, stream>>>(QL, KL, A2, LM, LM, DHEAD,
        DHEAD, DHEAD, LM, LM * DHEAD, LM * DHEAD, LM * LM, 1.f, 0.f);
    rowsoftmax256<<<2048, 256, 0, stream>>>(A2);
    colrow_max<<<8, 256, 0, stream>>>(A2, HM);
    denom_fin<<<1, 1, 0, stream>>>(HM, SC);
    transpose_scale<<<2048, 256, 0, stream>>>(A2, ZB, SC);
    float* zc = ZB; float* zn = Z2;
    for (int it = 0; it < 6; ++it) {
        gemm_k<0, 0><<<dim3(4, 2, 8), 256, 0, stream>>>(A2, zc, XZ, LM, LM, LM,
            LM, LM, LM, 65536, 65536, 65536, 1.f, 0.f);
        seven_i_minus<<<2048, 256, 0, stream>>>(XZ, WA);
        gemm_k<0, 4><<<dim3(4, 2, 8), 256, 0, stream>>>(XZ, WA, WB, LM, LM, LM,
            LM, LM, LM, 65536, 65536, 65536, 1.f, 15.f);
        gemm_k<0, 4><<<dim3(4, 2, 8), 256, 0, stream>>>(XZ, WB, WA, LM, LM, LM,
            LM, LM, LM, 65536, 65536, 65536, 1.f, 13.f);
        gemm_k<0, 0><<<dim3(4, 2, 8), 256, 0, stream>>>(zc, WA, zn, LM, LM, LM,
            LM, LM, LM, 65536, 65536, 65536, 0.25f, 0.f);
        float* t = zc; zc = zn; zn = t;
    }

    // ---- V transpose for PV3
    trans_b2b<<<dim3(2, 944, 8), 256, 0, stream>>>(Vh, VT, NPAD, 64, (ll)NPAD * 64, (ll)64 * NPAD);

    // ---- attn3 (batched over heads): logits bf16 -> stream softmax -> PV split-K
    bgemm<4><<<dim3(236, 2, 8), 256, 0, stream>>>(QLB, Kh, nullptr, P3,
        nullptr, nullptr, 256, NPAD, 64, 64, 64, NPAD, 0,
        (ll)256 * 64, (ll)NPAD * 64, (ll)256 * NPAD, 0, 1, 256, NPAD, 0);
    softmax_stream_b<<<2048, 256, 0, stream>>>(P3, RS);
    bgemm<5><<<dim3(1, 2, 128), 256, 0, stream>>>(P3, VT, KVP, nullptr,
        nullptr, nullptr, 256, 64, NPAD, NPAD, NPAD, 64, 0,
        (ll)256 * NPAD, (ll)64 * NPAD, (ll)16 * 16384, 16384, 16, 256, 64, 0);
    kv_reduce<<<512, 256, 0, stream>>>(KVP, RS, KV);

    // ---- PW = pinv(attn2) @ KV (fp32), then bf16 transpose
    gemm_k<0, 0><<<dim3(1, 2, 8), 256, 0, stream>>>(zc, KV, PW, LM, DHEAD, LM,
        LM, DHEAD, DHEAD, 65536, 16384, 16384, 1.f, 0.f);
    trans_f2b<<<dim3(2, 8, 8), 256, 0, stream>>>(PW, PWT, 256, 64, 16384, 16384);

    // ---- conv residual -> ATT (fp32)
    conv_res<<<dim3(7500, 8), 256, 0, stream>>>(Vh, conv_w, ATT);

    // ---- attn1 (2-head chunks): logits bf16 -> softmax -> += PV into ATT
    for (int hc = 0; hc < 8; hc += 2) {
        bgemm<4><<<dim3(2, 236, 2), 256, 0, stream>>>(Qh + (ll)hc * NPAD * 64,
            KLB + (ll)hc * 256 * 64, nullptr, P1, nullptr, nullptr,
            NPAD, 256, 64, 64, 64, 256, 0,
            (ll)NPAD * 64, (ll)256 * 64, (ll)NPAD * 256, 0, 1, NPAD, 256, 0);
        softmax256_b<<<2 * NPAD, 256, 0, stream>>>(P1);
        bgemm<6><<<dim3(1, 236, 2), 256, 0, stream>>>(P1, PWT + (ll)hc * 64 * 256,
            ATT + hc * 64, nullptr, nullptr, nullptr,
            NPAD, 64, 256, 256, 256, 512, 0,
            (ll)NPAD * 256, (ll)64 * 256, 64, 0, 1, 30000, 64, FPAD);
    }

    // ---- ATT -> bf16 (padded)
    att2attp<<<(int)(((ll)NPAD * 512) / 256), 256, 0, stream>>>(ATT, ATTP);

    // ---- out projection + bias + dense residual -> ENC (fp32 in d_out) + ENCB bf16
    zero_b16<<<832, 256, 0, stream>>>(ENCB + (ll)30000 * 1024, 208 * 1024);
    bgemm<2><<<dim3(8, 236, 1), 256, 0, stream>>>(ATTP, OUTWT, ENC, ENCB,
        out_b, dense, NPAD, 1024, 512, 512, 512, 1024, 1024,
        0, 0, 0, 0, 1, 30000, 1024, 0);

    // ---- q2 / k2 projections (fp32 out)
    bgemm<1><<<dim3(2, 236, 1), 256, 0, stream>>>(ENCB, WQT, Q2, nullptr,
        wq_b, nullptr, NPAD, 256, 1024, 1024, 1024, 256, 0,
        0, 0, 0, 0, 1, 30000, 256, 0);
    bgemm<1><<<dim3(2, 236, 1), 256, 0, stream>>>(ENCB, WKT, K2, nullptr,
        wk_b, nullptr, NPAD, 256, 1024, 1024, 1024, 256, 0,
        0, 0, 0, 0, 1, 30000, 256, 0);

    // ---- edges -> A_raw -> alpha
    zero_f32<<<(NSEQ + 255) / 256, 256, 0, stream>>>(ARAW, NSEQ);
    edge_scores<<<(E + 3) / 4, 256, 0, stream>>>(ei, adj, Q2, K2, ARAW, E);
    softmax30k_stats<<<1, 1024, 0, stream>>>(ARAW, SC);
    alpha_kernel<<<(NSEQ + 255) / 256, 256, 0, stream>>>(ARAW, SC, ALPHA);

    // ---- value = dense @ wv + b (bf16 MFMA, fp32 out)
    bgemm<1><<<dim3(8, 236, 1), 256, 0, stream>>>(DENSEP, WVT, VAL, nullptr,
        wv_b, nullptr, NPAD, 1024, 1024, 1024, 1024, 1024, 0,
        0, 0, 0, 0, 1, 30000, 1024, FPAD);

    // ---- final gating
    final_kernel<<<(int)(((ll)NSEQ * DMODEL) / 256), 256, 0, stream>>>(ALPHA, VAL, ENC, OUT);
}

// Round 3
// 1826.048 us; speedup vs baseline: 3.3251x; 1.3455x over previous
//
#include <hip/hip_runtime.h>

#define NSEQ   30000
#define NPAD   30208
#define FPAD   208
#define DMODEL 1024
#define NHEAD  8
#define DHEAD  64
#define LM     256
#define LCHUNK 118
#define INNER  512
#define NCHUNK 59     // NPAD / 512

typedef long long ll;
typedef unsigned short us;
typedef unsigned int uint32;
typedef __attribute__((ext_vector_type(8))) __bf16 bf16x8;
typedef __attribute__((ext_vector_type(4))) float f32x4;

__device__ __forceinline__ float b2f(us u) {
    union { unsigned int i; float f; } x; x.i = ((unsigned int)u) << 16; return x.f;
}
__device__ __forceinline__ us f2b(float f) {
    union { float f; unsigned int i; } x; x.f = f;
    unsigned int r = x.i + 0x7fffu + ((x.i >> 16) & 1u);
    return (us)(r >> 16);
}
__device__ __forceinline__ void gload16(const us* g, us* l) {
    __builtin_amdgcn_global_load_lds(
        (__attribute__((address_space(1))) void*)(const_cast<us*>(g)),
        (__attribute__((address_space(3))) void*)l, 16, 0, 0);
}

// ---------------------------------------------------------------------------
// bf16 MFMA GEMM: C = A(MxK) @ Bt(NxK)^T. 128x128 tile, BK=32, 4 waves.
// EPI: 0 C=acc; 1 C=acc+bias; 2 C=acc+bias+addp, +C2 bf16; 3 QKV scatter;
//      7 C2=bf16(acc), C3^T=bf16(7I-acc); 8 C3^T=bf16(diagv*I-acc);
//      9 C2=C3^T=bf16(0.25*acc); 10 C2=bf16(acc+bias);
//      11 fused value+gate: C = gate(alphap[r]*(acc+bias), C)
// ---------------------------------------------------------------------------
template<int EPI>
__global__ __launch_bounds__(256)
void bgemm(const us* __restrict__ A, const us* __restrict__ Bt,
           float* __restrict__ C, us* __restrict__ C2, us* __restrict__ C3,
           const float* __restrict__ bias, const float* __restrict__ addp,
           const float* __restrict__ alphap,
           int Mm, int Nn, int Kk, int lda, int ldb, int ldc, int ldadd,
           ll sA, ll sB, ll sC,
           int Mstore, int Nstore, int rSub, float diagv)
{
    __shared__ us As[128 * 32];
    __shared__ us Bs[128 * 32];

    int batch = blockIdx.z;
    A  += (ll)batch * sA;
    Bt += (ll)batch * sB;
    ll cOff = (ll)batch * sC;

    int m0 = blockIdx.y * 128, n0 = blockIdx.x * 128;
    int tid = threadIdx.x, w = tid >> 6, lane = tid & 63;
    int wr = w >> 1, wc = w & 1;
    int ktot = Kk >> 5;

    int q0 = w * 128;
    int qa0 = q0 + lane, qa1 = q0 + 64 + lane;
    int r0s = qa0 >> 2, c0s = (qa0 & 3) ^ ((r0s >> 1) & 3);
    int r1s = qa1 >> 2, c1s = (qa1 & 3) ^ ((r1s >> 1) & 3);
    int ar0 = m0 + r0s; if (ar0 > Mm - 1) ar0 = Mm - 1;
    int ar1 = m0 + r1s; if (ar1 > Mm - 1) ar1 = Mm - 1;
    int br0 = n0 + r0s; if (br0 > Nn - 1) br0 = Nn - 1;
    int br1 = n0 + r1s; if (br1 > Nn - 1) br1 = Nn - 1;
    const us* pa0 = A + (ll)ar0 * lda + c0s * 8;
    const us* pa1 = A + (ll)ar1 * lda + c1s * 8;
    const us* pb0 = Bt + (ll)br0 * ldb + c0s * 8;
    const us* pb1 = Bt + (ll)br1 * ldb + c1s * 8;
    us* la0 = &As[q0 * 8];
    us* la1 = &As[(q0 + 64) * 8];
    us* lb0 = &Bs[q0 * 8];
    us* lb1 = &Bs[(q0 + 64) * 8];

    int l15 = lane & 15, l4 = lane >> 4;
    int aoff[4], boff[4];
#pragma unroll
    for (int f = 0; f < 4; f++) {
        int row = wr * 64 + f * 16 + l15;
        aoff[f] = row * 32 + ((l4 ^ ((row >> 1) & 3)) << 3);
        int col = wc * 64 + f * 16 + l15;
        boff[f] = col * 32 + ((l4 ^ ((col >> 1) & 3)) << 3);
    }

    f32x4 acc[4][4];
#pragma unroll
    for (int i = 0; i < 4; i++)
#pragma unroll
        for (int j = 0; j < 4; j++) acc[i][j] = (f32x4){0.f, 0.f, 0.f, 0.f};

    for (int kt = 0; kt < ktot; ++kt) {
        int k0 = kt << 5;
        gload16(pa0 + k0, la0);
        gload16(pa1 + k0, la1);
        gload16(pb0 + k0, lb0);
        gload16(pb1 + k0, lb1);
        __syncthreads();
        bf16x8 af[4], bfr[4];
#pragma unroll
        for (int f = 0; f < 4; f++) af[f] = *(const bf16x8*)&As[aoff[f]];
#pragma unroll
        for (int f = 0; f < 4; f++) bfr[f] = *(const bf16x8*)&Bs[boff[f]];
#pragma unroll
        for (int i = 0; i < 4; i++)
#pragma unroll
            for (int j = 0; j < 4; j++)
                acc[i][j] = __builtin_amdgcn_mfma_f32_16x16x32_bf16(af[i], bfr[j], acc[i][j], 0, 0, 0);
        __syncthreads();
    }

#pragma unroll
    for (int fm = 0; fm < 4; fm++) {
        int rb = m0 + wr * 64 + fm * 16 + l4 * 4;
#pragma unroll
        for (int fn = 0; fn < 4; fn++) {
            int c = n0 + wc * 64 + fn * 16 + l15;
            if (c >= Nstore) continue;
#pragma unroll
            for (int i = 0; i < 4; i++) {
                int r = rb + i - rSub;
                if (r < 0 || r >= Mstore) continue;
                float v = acc[fm][fn][i];
                if (EPI == 0) C[cOff + (ll)r * ldc + c] = v;
                else if (EPI == 1) C[cOff + (ll)r * ldc + c] = v + bias[c];
                else if (EPI == 2) {
                    float o = v + bias[c] + addp[(ll)r * ldadd + c];
                    C[(ll)r * ldc + c] = o;
                    C2[(ll)r * ldc + c] = f2b(o);
                } else if (EPI == 3) {
                    int part = c >> 9, hh = (c >> 6) & 7, dd = c & 63;
                    float o = (part == 0) ? v * 0.125f : v;
                    C2[((ll)(part * 8 + hh) * NPAD + r) * 64 + dd] = f2b(o);
                } else if (EPI == 7) {
                    C2[cOff + (ll)r * 256 + c] = f2b(v);
                    C3[cOff + (ll)c * 256 + r] = f2b(((r == c) ? 7.0f : 0.0f) - v);
                } else if (EPI == 8) {
                    C3[cOff + (ll)c * 256 + r] = f2b(((r == c) ? diagv : 0.0f) - v);
                } else if (EPI == 9) {
                    us q = f2b(0.25f * v);
                    C2[cOff + (ll)r * 256 + c] = q;
                    C3[cOff + (ll)c * 256 + r] = q;
                } else if (EPI == 10) {
                    C2[(ll)r * ldc + c] = f2b(v + bias[c]);
                } else if (EPI == 11) {
                    float xl = alphap[r] * (v + bias[c]);
                    float enc = C[(ll)r * ldc + c];
                    float sg = 1.0f / (1.0f + __expf(xl));
                    float sw = sg * sg;
                    C[(ll)r * ldc + c] = xl * 2.0f * sw + 2.0f * enc * (1.0f - sw);
                }
            }
        }
    }
}

// ---------------------------------------------------------------------------
// fp32 GEMM (pinv refinement / attn2 / PW). TB=1: C=A@B^T. EPI 0: C=alpha*acc;
// EPI 4: C = diagv*I - acc.
#define BM 128
#define BN 64
#define BK 16
template<int TB, int EPI>
__global__ __launch_bounds__(256)
void gemm_k(const float* __restrict__ A, const float* __restrict__ B, float* __restrict__ C,
            int Mm, int Nn, int Kk, int lda, int ldb, int ldc,
            ll sA, ll sB, ll sC, float alpha, float diagv)
{
    __shared__ float As[BK][132];
    __shared__ float Bs[BK][68];
    int batch = blockIdx.z;
    A += (ll)batch * sA; B += (ll)batch * sB; C += (ll)batch * sC;
    int m0 = blockIdx.y * BM, n0 = blockIdx.x * BN;
    int tid = threadIdx.x, tx = tid & 15, ty = tid >> 4;
    int arow_t = tid >> 1, akh = (tid & 1) * 8;
    bool avalid = (m0 + arow_t < Mm);
    const float* Arow = A + (ll)(m0 + arow_t) * lda;
    float acc[8][4];
#pragma unroll
    for (int i = 0; i < 8; i++)
#pragma unroll
        for (int j = 0; j < 4; j++) acc[i][j] = 0.f;
    for (int kt = 0; kt < Kk / BK; ++kt) {
        int k0 = kt * BK;
        float4 av0 = make_float4(0, 0, 0, 0), av1 = av0;
        if (avalid) {
            av0 = *(const float4*)(Arow + k0 + akh);
            av1 = *(const float4*)(Arow + k0 + akh + 4);
        }
        float4 bv;
        if (TB == 0) bv = *(const float4*)(B + (ll)(k0 + (tid >> 4)) * ldb + n0 + (tid & 15) * 4);
        else         bv = *(const float4*)(B + (ll)(n0 + (tid >> 2)) * ldb + k0 + (tid & 3) * 4);
        __syncthreads();
        As[akh + 0][arow_t] = av0.x; As[akh + 1][arow_t] = av0.y;
        As[akh + 2][arow_t] = av0.z; As[akh + 3][arow_t] = av0.w;
        As[akh + 4][arow_t] = av1.x; As[akh + 5][arow_t] = av1.y;
        As[akh + 6][arow_t] = av1.z; As[akh + 7][arow_t] = av1.w;
        if (TB == 0) *(float4*)&Bs[tid >> 4][(tid & 15) * 4] = bv;
        else {
            int bk4 = (tid & 3) * 4, bn = tid >> 2;
            Bs[bk4 + 0][bn] = bv.x; Bs[bk4 + 1][bn] = bv.y;
            Bs[bk4 + 2][bn] = bv.z; Bs[bk4 + 3][bn] = bv.w;
        }
        __syncthreads();
#pragma unroll
        for (int kk = 0; kk < BK; kk++) {
            float ar[8], br[4];
            *(float4*)&ar[0] = *(const float4*)&As[kk][ty * 8];
            *(float4*)&ar[4] = *(const float4*)&As[kk][ty * 8 + 4];
            *(float4*)&br[0] = *(const float4*)&Bs[kk][tx * 4];
#pragma unroll
            for (int i = 0; i < 8; i++)
#pragma unroll
                for (int j = 0; j < 4; j++) acc[i][j] = fmaf(ar[i], br[j], acc[i][j]);
        }
    }
    int c0 = n0 + tx * 4;
#pragma unroll
    for (int i = 0; i < 8; i++) {
        int r = m0 + ty * 8 + i;
        if (r >= Mm) continue;
#pragma unroll
        for (int j = 0; j < 4; j++) {
            int c = c0 + j;
            if (c >= Nn) continue;
            float v = acc[i][j];
            if (EPI == 0) C[(ll)r * ldc + c] = alpha * v;
            else if (EPI == 4) C[(ll)r * ldc + c] = ((r == c) ? diagv : 0.f) - v;
        }
    }
}

// ---------------------------------------------------------------------------
// Fused attn3: KVpartial[h,chunk] = sum_{seq in chunk} exp(QL@K^T) V, Zpartial rowsums
__global__ __launch_bounds__(256)
void attn3_fused(const us* __restrict__ QLB, const us* __restrict__ Kh,
                 const us* __restrict__ VT, float* __restrict__ KVP,
                 float* __restrict__ ZP)
{
    __shared__ us sP[4][4096];
    int h = blockIdx.y, c0 = blockIdx.x * 512;
    int w = threadIdx.x >> 6, lane = threadIdx.x & 63;
    int l15 = lane & 15, l4 = lane >> 4;
    const us* QLh = QLB + (ll)h * 16384;
    const us* Khh = Kh + (ll)h * NPAD * 64;
    const us* VTh = VT + (ll)h * 64 * NPAD;
    us* P = sP[w];

    bf16x8 aq[4][2];
#pragma unroll
    for (int fm = 0; fm < 4; fm++)
#pragma unroll
        for (int ks = 0; ks < 2; ks++)
            aq[fm][ks] = *(const bf16x8*)&QLh[(w * 64 + fm * 16 + l15) * 64 + l4 * 8 + ks * 32];

    f32x4 acc2[4][4];
    float zacc[4][4];
#pragma unroll
    for (int a = 0; a < 4; a++)
#pragma unroll
        for (int b = 0; b < 4; b++) { acc2[a][b] = (f32x4){0.f,0.f,0.f,0.f}; zacc[a][b] = 0.f; }

    for (int sub = 0; sub < 8; ++sub) {
        int s0 = c0 + sub * 64;
        f32x4 s[4][4];
#pragma unroll
        for (int a = 0; a < 4; a++)
#pragma unroll
            for (int b = 0; b < 4; b++) s[a][b] = (f32x4){0.f,0.f,0.f,0.f};
#pragma unroll
        for (int ks = 0; ks < 2; ks++) {
            bf16x8 bk[4];
#pragma unroll
            for (int fn = 0; fn < 4; fn++)
                bk[fn] = *(const bf16x8*)&Khh[(ll)(s0 + fn * 16 + l15) * 64 + l4 * 8 + ks * 32];
#pragma unroll
            for (int fm = 0; fm < 4; fm++)
#pragma unroll
                for (int fn = 0; fn < 4; fn++)
                    s[fm][fn] = __builtin_amdgcn_mfma_f32_16x16x32_bf16(aq[fm][ks], bk[fn], s[fm][fn], 0, 0, 0);
        }
#pragma unroll
        for (int fm = 0; fm < 4; fm++)
#pragma unroll
            for (int i = 0; i < 4; i++) {
                int row = fm * 16 + l4 * 4 + i;
#pragma unroll
                for (int fn = 0; fn < 4; fn++) {
                    float e = __expf(s[fm][fn][i]);
                    zacc[fm][i] += e;
                    int col = fn * 16 + l15;
                    P[row * 64 + (((col >> 3) ^ (row & 7)) << 3) + (col & 7)] = f2b(e);
                }
            }
#pragma unroll
        for (int ks = 0; ks < 2; ks++) {
            bf16x8 ap[4], bv[4];
#pragma unroll
            for (int fm = 0; fm < 4; fm++) {
                int row = fm * 16 + l15;
                int ch = (l4 + ks * 4) ^ (row & 7);
                ap[fm] = *(const bf16x8*)&P[row * 64 + ch * 8];
            }
#pragma unroll
            for (int fn = 0; fn < 4; fn++)
                bv[fn] = *(const bf16x8*)&VTh[(ll)(fn * 16 + l15) * NPAD + s0 + l4 * 8 + ks * 32];
#pragma unroll
            for (int fm = 0; fm < 4; fm++)
#pragma unroll
                for (int fn = 0; fn < 4; fn++)
                    acc2[fm][fn] = __builtin_amdgcn_mfma_f32_16x16x32_bf16(ap[fm], bv[fn], acc2[fm][fn], 0, 0, 0);
        }
    }
    float* KP = KVP + ((ll)h * NCHUNK + blockIdx.x) * 16384;
#pragma unroll
    for (int fm = 0; fm < 4; fm++)
#pragma unroll
        for (int fn = 0; fn < 4; fn++)
#pragma unroll
            for (int i = 0; i < 4; i++)
                KP[(w * 64 + fm * 16 + l4 * 4 + i) * 64 + fn * 16 + l15] = acc2[fm][fn][i];
#pragma unroll
    for (int fm = 0; fm < 4; fm++)
#pragma unroll
        for (int i = 0; i < 4; i++) {
            float zz = zacc[fm][i];
            zz += __shfl_xor(zz, 1, 64); zz += __shfl_xor(zz, 2, 64);
            zz += __shfl_xor(zz, 4, 64); zz += __shfl_xor(zz, 8, 64);
            if (l15 == 0)
                ZP[((ll)h * NCHUNK + blockIdx.x) * 256 + w * 64 + fm * 16 + l4 * 4 + i] = zz;
        }
}

__global__ void kv_reduce2(const float* __restrict__ KVP, const float* __restrict__ ZP,
                           float* __restrict__ KV)
{
    int e = blockIdx.x * 256 + threadIdx.x;   // < 131072
    int h = e >> 14, r = (e >> 6) & 255;
    float s = 0.f, z = 0.f;
    for (int c = 0; c < NCHUNK; ++c) {
        s += KVP[((ll)h * NCHUNK + c) * 16384 + (e & 16383)];
        z += ZP[((ll)h * NCHUNK + c) * 256 + r];
    }
    KV[e] = s / z;
}

// ---------------------------------------------------------------------------
// Fused attn1: ATTP[r, h*64+d] = bf16( softmax(Q@KL^T) @ PW + ATT[r, h*64+d] )
__global__ __launch_bounds__(256)
void attn1_fused(const us* __restrict__ Qh, const us* __restrict__ KLB,
                 const us* __restrict__ PWT, const float* __restrict__ ATT,
                 us* __restrict__ ATTP)
{
    __shared__ us sP[4][4096];
    int h = blockIdx.y, r0 = blockIdx.x * 128;
    int w = threadIdx.x >> 6, lane = threadIdx.x & 63;
    int l15 = lane & 15, l4 = lane >> 4;
    const us* Qhh = Qh + (ll)h * NPAD * 64;
    const us* KLh = KLB + (ll)h * 16384;
    const us* PWh = PWT + (ll)h * 16384;
    us* P = sP[w];

    bf16x8 aq[2][2];
#pragma unroll
    for (int fm = 0; fm < 2; fm++)
#pragma unroll
        for (int ks = 0; ks < 2; ks++) {
            int r = r0 + w * 32 + fm * 16 + l15;
            if (r > NSEQ - 1) r = NSEQ - 1;
            aq[fm][ks] = *(const bf16x8*)&Qhh[(ll)(r + FPAD) * 64 + l4 * 8 + ks * 32];
        }

    f32x4 s[2][16];
#pragma unroll
    for (int a = 0; a < 2; a++)
#pragma unroll
        for (int b = 0; b < 16; b++) s[a][b] = (f32x4){0.f,0.f,0.f,0.f};
#pragma unroll
    for (int ks = 0; ks < 2; ks++)
#pragma unroll
        for (int fn = 0; fn < 16; fn++) {
            bf16x8 bk = *(const bf16x8*)&KLh[(fn * 16 + l15) * 64 + l4 * 8 + ks * 32];
            s[0][fn] = __builtin_amdgcn_mfma_f32_16x16x32_bf16(aq[0][ks], bk, s[0][fn], 0, 0, 0);
            s[1][fn] = __builtin_amdgcn_mfma_f32_16x16x32_bf16(aq[1][ks], bk, s[1][fn], 0, 0, 0);
        }
    // exact softmax across 256 cols
#pragma unroll
    for (int fm = 0; fm < 2; fm++)
#pragma unroll
        for (int i = 0; i < 4; i++) {
            float m = s[fm][0][i];
#pragma unroll
            for (int fn = 1; fn < 16; fn++) m = fmaxf(m, s[fm][fn][i]);
            m = fmaxf(m, __shfl_xor(m, 1, 64)); m = fmaxf(m, __shfl_xor(m, 2, 64));
            m = fmaxf(m, __shfl_xor(m, 4, 64)); m = fmaxf(m, __shfl_xor(m, 8, 64));
            float sum = 0.f;
#pragma unroll
            for (int fn = 0; fn < 16; fn++) {
                float e = __expf(s[fm][fn][i] - m);
                s[fm][fn][i] = e; sum += e;
            }
            sum += __shfl_xor(sum, 1, 64); sum += __shfl_xor(sum, 2, 64);
            sum += __shfl_xor(sum, 4, 64); sum += __shfl_xor(sum, 8, 64);
            float rinv = 1.0f / sum;
#pragma unroll
            for (int fn = 0; fn < 16; fn++) s[fm][fn][i] *= rinv;
        }
    // PV in two 128-col halves through per-wave LDS
    f32x4 acc2[2][4];
#pragma unroll
    for (int a = 0; a < 2; a++)
#pragma unroll
        for (int b = 0; b < 4; b++) acc2[a][b] = (f32x4){0.f,0.f,0.f,0.f};
#pragma unroll
    for (int half = 0; half < 2; ++half) {
#pragma unroll
        for (int fm = 0; fm < 2; fm++)
#pragma unroll
            for (int i = 0; i < 4; i++) {
                int row = fm * 16 + l4 * 4 + i;
#pragma unroll
                for (int fh = 0; fh < 8; fh++) {
                    int col = fh * 16 + l15;
                    P[row * 128 + (((col >> 3) ^ (row & 7)) << 3) + (col & 7)] =
                        f2b(s[fm][half * 8 + fh][i]);
                }
            }
#pragma unroll
        for (int ks = 0; ks < 4; ks++) {
            bf16x8 ap[2];
#pragma unroll
            for (int fm = 0; fm < 2; fm++) {
                int row = fm * 16 + l15;
                int ch = (l4 + ks * 4) ^ (row & 7);
                ap[fm] = *(const bf16x8*)&P[row * 128 + ch * 8];
            }
#pragma unroll
            for (int fn = 0; fn < 4; fn++) {
                bf16x8 bp = *(const bf16x8*)&PWh[(ll)(fn * 16 + l15) * 256 + half * 128 + l4 * 8 + ks * 32];
                acc2[0][fn] = __builtin_amdgcn_mfma_f32_16x16x32_bf16(ap[0], bp, acc2[0][fn], 0, 0, 0);
                acc2[1][fn] = __builtin_amdgcn_mfma_f32_16x16x32_bf16(ap[1], bp, acc2[1][fn], 0, 0, 0);
            }
        }
    }
#pragma unroll
    for (int fm = 0; fm < 2; fm++)
#pragma unroll
        for (int fn = 0; fn < 4; fn++)
#pragma unroll
            for (int i = 0; i < 4; i++) {
                int r = r0 + w * 32 + fm * 16 + l4 * 4 + i;
                if (r < NSEQ) {
                    int d = fn * 16 + l15;
                    float a = acc2[fm][fn][i] + ATT[(ll)r * 512 + h * 64 + d];
                    ATTP[(ll)r * 512 + h * 64 + d] = f2b(a);
                }
            }
}

// ---------------------------------------------------------------------------
__global__ void trans_f2b(const float* __restrict__ in, us* __restrict__ out,
                          int R, int Cc, ll sI, ll sO)
{
    __shared__ float tile[32][33];
    const float* inp = in + (ll)blockIdx.z * sI;
    us* outp = out + (ll)blockIdx.z * sO;
    int r0 = blockIdx.y * 32, c0 = blockIdx.x * 32;
    int tx = threadIdx.x & 31, ty = threadIdx.x >> 5;
#pragma unroll
    for (int i = 0; i < 4; i++) {
        int r = r0 + ty + i * 8, c = c0 + tx;
        tile[ty + i * 8][tx] = (r < R && c < Cc) ? inp[(ll)r * Cc + c] : 0.f;
    }
    __syncthreads();
#pragma unroll
    for (int i = 0; i < 4; i++) {
        int c = c0 + ty + i * 8, r = r0 + tx;
        if (c < Cc && r < R) outp[(ll)c * R + r] = f2b(tile[tx][ty + i * 8]);
    }
}

__global__ void trans_b2b(const us* __restrict__ in, us* __restrict__ out,
                          int R, int Cc, ll sI, ll sO)
{
    __shared__ us tile[32][34];
    const us* inp = in + (ll)blockIdx.z * sI;
    us* outp = out + (ll)blockIdx.z * sO;
    int r0 = blockIdx.y * 32, c0 = blockIdx.x * 32;
    int tx = threadIdx.x & 31, ty = threadIdx.x >> 5;
#pragma unroll
    for (int i = 0; i < 4; i++) {
        int r = r0 + ty + i * 8, c = c0 + tx;
        tile[ty + i * 8][tx] = (r < R && c < Cc) ? inp[(ll)r * Cc + c] : (us)0;
    }
    __syncthreads();
#pragma unroll
    for (int i = 0; i < 4; i++) {
        int c = c0 + ty + i * 8, r = r0 + tx;
        if (c < Cc && r < R) outp[(ll)c * R + r] = tile[tx][ty + i * 8];
    }
}

__global__ void dense_pad_b(const float* __restrict__ x, us* __restrict__ o)
{
    ll e4 = ((ll)blockIdx.x * 256 + threadIdx.x) * 4;
    int r = (int)(e4 >> 10), c = (int)(e4 & 1023);
    ushort4 u;
    if (r < FPAD) { u.x = u.y = u.z = u.w = 0; }
    else {
        float4 v = *(const float4*)&x[(ll)(r - FPAD) * 1024 + c];
        u.x = f2b(v.x); u.y = f2b(v.y); u.z = f2b(v.z); u.w = f2b(v.w);
    }
    *(ushort4*)&o[e4] = u;
}

__global__ void f2b_vec(const float* __restrict__ in, us* __restrict__ out, int n)
{
    int i = blockIdx.x * 256 + threadIdx.x;
    if (i < n) out[i] = f2b(in[i]);
}

__global__ void landmark_mean_b(const us* __restrict__ src, float* __restrict__ dst)
{
    int b = blockIdx.x;
    int h = b >> 8, jm = b & 255;
    int d = threadIdx.x;
    const us* p = src + ((ll)h * NPAD + (ll)jm * LCHUNK) * DHEAD + d;
    float s = 0.f;
    for (int jl = 0; jl < LCHUNK; ++jl) s += b2f(p[jl * DHEAD]);
    dst[((h << 8) + jm) * DHEAD + d] = s * (1.0f / LCHUNK);
}

__global__ void rowsoftmax256(float* __restrict__ X)
{
    __shared__ float red[256];
    float* p = X + (ll)blockIdx.x * 256;
    int t = threadIdx.x;
    float v = p[t];
    red[t] = v; __syncthreads();
    for (int s = 128; s > 0; s >>= 1) { if (t < s) red[t] = fmaxf(red[t], red[t + s]); __syncthreads(); }
    float m = red[0]; __syncthreads();
    float e = expf(v - m);
    red[t] = e; __syncthreads();
    for (int s = 128; s > 0; s >>= 1) { if (t < s) red[t] += red[t + s]; __syncthreads(); }
    p[t] = e / red[0];
}

__global__ void colrow_max(const float* __restrict__ A2, float* __restrict__ hm)
{
    __shared__ float red[256];
    int h = blockIdx.x, t = threadIdx.x;
    const float* X = A2 + (ll)h * LM * LM;
    float cs = 0.f;
    for (int i = 0; i < LM; ++i) cs += X[i * LM + t];
    red[t] = cs; __syncthreads();
    for (int s = 128; s > 0; s >>= 1) { if (t < s) red[t] = fmaxf(red[t], red[t + s]); __syncthreads(); }
    if (t == 0) hm[h] = red[0];
    __syncthreads();
    float rs = 0.f;
    const float* Xr = X + (ll)t * LM;
    for (int j = 0; j < LM; ++j) rs += Xr[j];
    red[t] = rs; __syncthreads();
    for (int s = 128; s > 0; s >>= 1) { if (t < s) red[t] = fmaxf(red[t], red[t + s]); __syncthreads(); }
    if (t == 0) hm[8 + h] = red[0];
}

__global__ void denom_fin(const float* __restrict__ hm, float* __restrict__ scal)
{
    float cm = hm[0], rm = hm[8];
    for (int h = 1; h < 8; ++h) { cm = fmaxf(cm, hm[h]); rm = fmaxf(rm, hm[8 + h]); }
    scal[0] = 1.0f / (cm * rm);
}

// XN = bf16(A2); ZT0 = bf16(A2*scal); ZN0[c][r] = bf16(A2[r][c]*scal)
__global__ void pinv_init(const float* __restrict__ A2, const float* __restrict__ scal,
                          us* __restrict__ XN, us* __restrict__ ZN, us* __restrict__ ZT)
{
    ll e = (ll)blockIdx.x * 256 + threadIdx.x;
    int h = (int)(e >> 16), r = (int)(e >> 8) & 255, c = (int)e & 255;
    float v = A2[e];
    XN[e] = f2b(v);
    float vs = v * scal[0];
    ZT[e] = f2b(vs);
    ZN[((ll)h << 16) + ((ll)c << 8) + r] = f2b(vs);
}

__global__ void zwiden(const us* __restrict__ zn, float* __restrict__ zf)
{
    ll e = (ll)blockIdx.x * 256 + threadIdx.x;
    zf[e] = b2f(zn[e]);
}

__global__ void seven_i_minus(const float* __restrict__ XZ, float* __restrict__ Wo)
{
    ll e = (ll)blockIdx.x * 256 + threadIdx.x;
    int r = (int)(e >> 8) & 255; int c = (int)e & 255;
    Wo[e] = ((r == c) ? 7.0f : 0.0f) - XZ[e];
}

__global__ void conv_res(const us* __restrict__ V, const float* __restrict__ cw,
                         float* __restrict__ ATT)
{
    int h = blockIdx.y;
    int i = blockIdx.x * 4 + (threadIdx.x >> 6);
    int d = threadIdx.x & 63;
    if (i >= NSEQ) return;
    const us* Vh = V + (ll)h * NPAD * DHEAD;
    int n0 = FPAD + i - 16;
    float s = 0.f;
#pragma unroll
    for (int kk = 0; kk < 33; ++kk) {
        int n = n0 + kk;
        if (n < NPAD) s += cw[h * 33 + kk] * b2f(Vh[(ll)n * DHEAD + d]);
    }
    ATT[(ll)i * INNER + h * DHEAD + d] = s;
}

__global__ void zero_f32(float* __restrict__ p, int n)
{
    int i = blockIdx.x * 256 + threadIdx.x;
    if (i < n) p[i] = 0.f;
}

__global__ void edge_scores_b(const int* __restrict__ ei, const float* __restrict__ adj,
                              const us* __restrict__ q2, const us* __restrict__ k2,
                              float* __restrict__ Araw, int E)
{
    int gw = (blockIdx.x * 256 + threadIdx.x) >> 6;
    int lane = threadIdx.x & 63;
    if (gw >= E) return;
    int src = ei[gw], dst = ei[E + gw];
    const uint32* qp = (const uint32*)(q2 + (ll)src * 256);
    const uint32* kp = (const uint32*)(k2 + (ll)dst * 256);
    float acc = 0.f;
#pragma unroll
    for (int t = 0; t < 2; t++) {
        uint32 qu = qp[lane + t * 64], ku = kp[lane + t * 64];
        acc += b2f((us)(qu & 0xffff)) * b2f((us)(ku & 0xffff));
        acc += b2f((us)(qu >> 16)) * b2f((us)(ku >> 16));
    }
#pragma unroll
    for (int m = 32; m >= 1; m >>= 1) acc += __shfl_xor(acc, m, 64);
    if (lane == 0) atomicAdd(Araw + src, acc * adj[gw] * 0.0625f);
}

__global__ void softmax30k_stats(const float* __restrict__ A, float* __restrict__ scal)
{
    __shared__ float red[1024];
    int t = threadIdx.x;
    float m = -3.0e38f;
    for (int i = t; i < NSEQ; i += 1024) m = fmaxf(m, A[i]);
    red[t] = m; __syncthreads();
    for (int s = 512; s > 0; s >>= 1) { if (t < s) red[t] = fmaxf(red[t], red[t + s]); __syncthreads(); }
    m = red[0]; __syncthreads();
    float sum = 0.f;
    for (int i = t; i < NSEQ; i += 1024) sum += expf(A[i] - m);
    red[t] = sum; __syncthreads();
    for (int s = 512; s > 0; s >>= 1) { if (t < s) red[t] += red[t + s]; __syncthreads(); }
    if (t == 0) { scal[1] = m; scal[2] = red[0]; }
}

__global__ void alpha_kernel(const float* __restrict__ A, const float* __restrict__ scal,
                             float* __restrict__ alpha)
{
    int i = blockIdx.x * 256 + threadIdx.x;
    if (i < NSEQ) alpha[i] = expf(A[i] - scal[1]) / scal[2];
}

// ---------------------------------------------------------------------------
extern "C" void kernel_launch(void* const* d_in, const int* in_sizes, int n_in,
                              void* d_out, int out_size, void* d_ws, size_t ws_size,
                              hipStream_t stream)
{
    const float* dense  = (const float*)d_in[0];
    const int*   ei     = (const int*)d_in[1];
    const float* adj    = (const float*)d_in[2];
    const float* qkv_w  = (const float*)d_in[3];
    const float* out_w  = (const float*)d_in[4];
    const float* out_b  = (const float*)d_in[5];
    const float* conv_w = (const float*)d_in[6];
    const float* wq_w   = (const float*)d_in[7];
    const float* wq_b   = (const float*)d_in[8];
    const float* wk_w   = (const float*)d_in[9];
    const float* wk_b   = (const float*)d_in[10];
    const float* wv_w   = (const float*)d_in[11];
    const float* wv_b   = (const float*)d_in[12];
    int E = in_sizes[2];

    char* w = (char*)d_ws;
    auto alloc = [&](ll bytes) { char* p = w; w += (bytes + 255) & ~(ll)255; return p; };

    us*    DENSEP = (us*)alloc((ll)NPAD * 1024 * 2);
    us*    QKVH   = (us*)alloc((ll)3 * 8 * NPAD * 64 * 2);
    us*    ENCB   = QKVH;                         // alias: QKVH dead before out-proj writes ENCB
    us*    Qh = QKVH, *Kh = QKVH + (ll)8 * NPAD * 64, *Vh = QKVH + (ll)16 * NPAD * 64;
    us*    VT     = (us*)alloc((ll)8 * 64 * NPAD * 2);
    us*    QKVWT  = (us*)alloc((ll)1536 * 1024 * 2);
    us*    OUTWT  = (us*)alloc((ll)1024 * 512 * 2);
    us*    WQT    = (us*)alloc((ll)256 * 1024 * 2);
    us*    WKT    = (us*)alloc((ll)256 * 1024 * 2);
    us*    WVT    = (us*)alloc((ll)1024 * 1024 * 2);
    float* QL     = (float*)alloc((ll)8 * 256 * 64 * 4);
    float* KL     = (float*)alloc((ll)8 * 256 * 64 * 4);
    us*    QLB    = (us*)alloc((ll)8 * 256 * 64 * 2);
    us*    KLB    = (us*)alloc((ll)8 * 256 * 64 * 2);
    float* A2     = (float*)alloc((ll)8 * 65536 * 4);
    us*    XN     = (us*)alloc((ll)8 * 65536 * 2);
    us*    ZN     = (us*)alloc((ll)8 * 65536 * 2);
    us*    ZT     = (us*)alloc((ll)8 * 65536 * 2);
    us*    ZN2    = (us*)alloc((ll)8 * 65536 * 2);
    us*    ZT2    = (us*)alloc((ll)8 * 65536 * 2);
    us*    XZN    = (us*)alloc((ll)8 * 65536 * 2);
    us*    W1T    = (us*)alloc((ll)8 * 65536 * 2);
    us*    W2T    = (us*)alloc((ll)8 * 65536 * 2);
    us*    W3T    = (us*)alloc((ll)8 * 65536 * 2);
    float* ZF     = (float*)alloc((ll)8 * 65536 * 4);
    float* ZC     = (float*)alloc((ll)8 * 65536 * 4);
    float* XZF    = (float*)alloc((ll)8 * 65536 * 4);
    float* WAF    = (float*)alloc((ll)8 * 65536 * 4);
    float* WBF    = (float*)alloc((ll)8 * 65536 * 4);
    float* KVP    = (float*)alloc((ll)8 * NCHUNK * 16384 * 4);
    float* ZP     = (float*)alloc((ll)8 * NCHUNK * 256 * 4);
    float* KV     = (float*)alloc((ll)8 * 16384 * 4);
    float* PW     = (float*)alloc((ll)8 * 16384 * 4);
    us*    PWT    = (us*)alloc((ll)8 * 16384 * 2);
    float* HM     = (float*)alloc(64 * 4);
    float* SC     = (float*)alloc(64 * 4);
    float* ALPHA  = (float*)alloc(30000 * 4);
    float* ATT    = (float*)alloc((ll)NSEQ * 512 * 4);
    us*    ATTP   = (us*)alloc((ll)NSEQ * 512 * 2);
    us*    Q2B    = (us*)ATT;                     // alias: ATT dead after attn1
    us*    K2B    = (us*)(ATT + (ll)NSEQ * 256);  // (offset in floats = NSEQ*256*4B)

    float* OUT  = (float*)d_out;
    float* ENC  = OUT;
    float* ARAW = OUT + (ll)NSEQ * DMODEL;

    // ---- prep
    trans_f2b<<<dim3(48, 32, 1), 256, 0, stream>>>(qkv_w, QKVWT, 1024, 1536, 0, 0);
    trans_f2b<<<dim3(32, 16, 1), 256, 0, stream>>>(out_w, OUTWT, 512, 1024, 0, 0);
    trans_f2b<<<dim3(8, 32, 1), 256, 0, stream>>>(wq_w, WQT, 1024, 256, 0, 0);
    trans_f2b<<<dim3(8, 32, 1), 256, 0, stream>>>(wk_w, WKT, 1024, 256, 0, 0);
    trans_f2b<<<dim3(32, 32, 1), 256, 0, stream>>>(wv_w, WVT, 1024, 1024, 0, 0);
    dense_pad_b<<<NPAD, 256, 0, stream>>>(dense, DENSEP);

    // ---- QKV projection -> per-head bf16 Q,K,V (q pre-scaled by 1/8)
    bgemm<3><<<dim3(12, 236, 1), 256, 0, stream>>>(DENSEP, QKVWT, nullptr, QKVH, nullptr,
        nullptr, nullptr, nullptr, NPAD, 1536, 1024, 1024, 1024, 0, 0,
        0, 0, 0, NPAD, 1536, 0, 0.f);

    // ---- landmarks
    landmark_mean_b<<<2048, 64, 0, stream>>>(Qh, QL);
    landmark_mean_b<<<2048, 64, 0, stream>>>(Kh, KL);
    f2b_vec<<<512, 256, 0, stream>>>(QL, QLB, 131072);
    f2b_vec<<<512, 256, 0, stream>>>(KL, KLB, 131072);

    // ---- attn2 (fp32) + denom
    gemm_k<1, 0><<<dim3(4, 2, 8), 256, 0, stream>>>(QL, KL, A2, LM, LM, DHEAD,
        DHEAD, DHEAD, LM, LM * DHEAD, LM * DHEAD, LM * LM, 1.f, 0.f);
    rowsoftmax256<<<2048, 256, 0, stream>>>(A2);
    colrow_max<<<8, 256, 0, stream>>>(A2, HM);
    denom_fin<<<1, 1, 0, stream>>>(HM, SC);
    pinv_init<<<2048, 256, 0, stream>>>(A2, SC, XN, ZN, ZT);

    // ---- 6 bf16 Moore-Penrose iterations (transposed-operand scheme)
    us* znc = ZN; us* ztc = ZT; us* znn = ZN2; us* ztn = ZT2;
    for (int it = 0; it < 6; ++it) {
        bgemm<7><<<dim3(2, 2, 8), 256, 0, stream>>>(XN, ztc, nullptr, XZN, W1T,
            nullptr, nullptr, nullptr, 256, 256, 256, 256, 256, 256, 0,
            65536, 65536, 65536, 256, 256, 0, 0.f);
        bgemm<8><<<dim3(2, 2, 8), 256, 0, stream>>>(XZN, W1T, nullptr, nullptr, W2T,
            nullptr, nullptr, nullptr, 256, 256, 256, 256, 256, 256, 0,
            65536, 65536, 65536, 256, 256, 0, 15.f);
        bgemm<8><<<dim3(2, 2, 8), 256, 0, stream>>>(XZN, W2T, nullptr, nullptr, W3T,
            nullptr, nullptr, nullptr, 256, 256, 256, 256, 256, 256, 0,
            65536, 65536, 65536, 256, 256, 0, 13.f);
        bgemm<9><<<dim3(2, 2, 8), 256, 0, stream>>>(znc, W3T, nullptr, znn, ztn,
            nullptr, nullptr, nullptr, 256, 256, 256, 256, 256, 256, 0,
            65536, 65536, 65536, 256, 256, 0, 0.f);
        us* t;
        t = znc; znc = znn; znn = t;
        t = ztc; ztc = ztn; ztn = t;
    }
    // ---- final fp32 refinement iteration
    zwiden<<<2048, 256, 0, stream>>>(znc, ZF);
    gemm_k<0, 0><<<dim3(4, 2, 8), 256, 0, stream>>>(A2, ZF, XZF, LM, LM, LM,
        LM, LM, LM, 65536, 65536, 65536, 1.f, 0.f);
    seven_i_minus<<<2048, 256, 0, stream>>>(XZF, WAF);
    gemm_k<0, 4><<<dim3(4, 2, 8), 256, 0, stream>>>(XZF, WAF, WBF, LM, LM, LM,
        LM, LM, LM, 65536, 65536, 65536, 1.f, 15.f);
    gemm_k<0, 4><<<dim3(4, 2, 8), 256, 0, stream>>>(XZF, WBF, WAF, LM, LM, LM,
        LM, LM, LM, 65536, 65536, 65536, 1.f, 13.f);
    gemm_k<0, 0><<<dim3(4, 2, 8), 256, 0, stream>>>(ZF, WAF, ZC, LM, LM, LM,
        LM, LM, LM, 65536, 65536, 65536, 0.25f, 0.f);

    // ---- V transpose, fused attn3, KV
    trans_b2b<<<dim3(2, 944, 8), 256, 0, stream>>>(Vh, VT, NPAD, 64, (ll)NPAD * 64, (ll)64 * NPAD);
    attn3_fused<<<dim3(NCHUNK, 8), 256, 0, stream>>>(QLB, Kh, VT, KVP, ZP);
    kv_reduce2<<<512, 256, 0, stream>>>(KVP, ZP, KV);

    // ---- PW = pinv(attn2) @ KV ; PWT
    gemm_k<0, 0><<<dim3(1, 2, 8), 256, 0, stream>>>(ZC, KV, PW, LM, DHEAD, LM,
        LM, DHEAD, DHEAD, 65536, 16384, 16384, 1.f, 0.f);
    trans_f2b<<<dim3(2, 8, 8), 256, 0, stream>>>(PW, PWT, 256, 64, 16384, 16384);

    // ---- conv residual, fused attn1 (+conv add) -> ATTP bf16
    conv_res<<<dim3(7500, 8), 256, 0, stream>>>(Vh, conv_w, ATT);
    attn1_fused<<<dim3(235, 8), 256, 0, stream>>>(Qh, KLB, PWT, ATT, ATTP);

    // ---- out projection + bias + dense residual -> ENC fp32 (d_out) + ENCB bf16
    bgemm<2><<<dim3(8, 235, 1), 256, 0, stream>>>(ATTP, OUTWT, ENC, ENCB, nullptr,
        out_b, dense, nullptr, NSEQ, 1024, 512, 512, 512, 1024, 1024,
        0, 0, 0, NSEQ, 1024, 0, 0.f);

    // ---- q2 / k2 projections (bf16 out)
    bgemm<10><<<dim3(2, 235, 1), 256, 0, stream>>>(ENCB, WQT, nullptr, Q2B, nullptr,
        wq_b, nullptr, nullptr, NSEQ, 256, 1024, 1024, 1024, 256, 0,
        0, 0, 0, NSEQ, 256, 0, 0.f);
    bgemm<10><<<dim3(2, 235, 1), 256, 0, stream>>>(ENCB, WKT, nullptr, K2B, nullptr,
        wk_b, nullptr, nullptr, NSEQ, 256, 1024, 1024, 1024, 256, 0,
        0, 0, 0, NSEQ, 256, 0, 0.f);

    // ---- edges -> A_raw -> alpha
    zero_f32<<<(NSEQ + 255) / 256, 256, 0, stream>>>(ARAW, NSEQ);
    edge_scores_b<<<(E + 3) / 4, 256, 0, stream>>>(ei, adj, Q2B, K2B, ARAW, E);
    softmax30k_stats<<<1, 1024, 0, stream>>>(ARAW, SC);
    alpha_kernel<<<(NSEQ + 255) / 256, 256, 0, stream>>>(ARAW, SC, ALPHA);

    // ---- fused value + gating (reads ENC in place, writes xo)
    bgemm<11><<<dim3(8, 235, 1), 256, 0, stream>>>(DENSEP + (ll)FPAD * 1024, WVT, OUT,
        nullptr, nullptr, wv_b, nullptr, ALPHA, NSEQ, 1024, 1024, 1024, 1024, 1024, 0,
        0, 0, 0, NSEQ, 1024, 0, 0.f);
}

// Round 4
// 1716.325 us; speedup vs baseline: 3.5377x; 1.0639x over previous
//
#include <hip/hip_runtime.h>

#define NSEQ   30000
#define NPAD   30208
#define FPAD   208
#define DMODEL 1024
#define NHEAD  8
#define DHEAD  64
#define LM     256
#define LCHUNK 118
#define INNER  512
#define NCHUNK 59     // NPAD / 512
#define PINV_BLOCKS 32

typedef long long ll;
typedef unsigned short us;
typedef unsigned int uint32;
typedef __attribute__((ext_vector_type(8))) __bf16 bf16x8;
typedef __attribute__((ext_vector_type(4))) float f32x4;

__device__ __forceinline__ float b2f(us u) {
    union { unsigned int i; float f; } x; x.i = ((unsigned int)u) << 16; return x.f;
}
__device__ __forceinline__ us f2b(float f) {
    union { float f; unsigned int i; } x; x.f = f;
    unsigned int r = x.i + 0x7fffu + ((x.i >> 16) & 1u);
    return (us)(r >> 16);
}
__device__ __forceinline__ void gload16(const us* g, us* l) {
    __builtin_amdgcn_global_load_lds(
        (__attribute__((address_space(1))) void*)(const_cast<us*>(g)),
        (__attribute__((address_space(3))) void*)l, 16, 0, 0);
}

// ---------------------------------------------------------------------------
// bf16 MFMA GEMM, 128x128 tile, BK=32, 4 waves. 2-phase double-buffered LDS
// pipeline: stage(next) -> vmcnt(4) -> barrier -> ds_read+MFMA(cur) -> barrier.
// Never drains vmcnt to 0 in the main loop (T3/T4). XCD-bijective swizzle (T1).
// EPI: 2 C=acc+bias+addp (fp32) + C2 bf16; 3 QKV scatter (q*0.125);
//      10 C2=bf16(acc+bias); 11 fused value+gate: C=gate(alphap[r]*(acc+bias), C)
// ---------------------------------------------------------------------------
template<int EPI>
__global__ __launch_bounds__(256)
void bgemm(const us* __restrict__ A, const us* __restrict__ Bt,
           float* __restrict__ C, us* __restrict__ C2,
           const float* __restrict__ bias, const float* __restrict__ addp,
           const float* __restrict__ alphap,
           int Mm, int Nn, int Kk, int lda, int ldb, int ldc, int ldadd,
           int Mstore, int Nstore, int rSub)
{
    __shared__ us As[2][128 * 32];
    __shared__ us Bs[2][128 * 32];

    // XCD-bijective block swizzle (m204): contiguous tile chunk per XCD
    int nwg = gridDim.x * gridDim.y;
    int orig = blockIdx.y * gridDim.x + blockIdx.x;
    int qd = nwg >> 3, rm = nwg & 7;
    int xcd = orig & 7, off = orig >> 3;
    int swz = (xcd < rm ? xcd * (qd + 1) : rm * (qd + 1) + (xcd - rm) * qd) + off;
    int by = swz / gridDim.x, bx = swz - by * gridDim.x;
    int m0 = by * 128, n0 = bx * 128;

    int tid = threadIdx.x, w = tid >> 6, lane = tid & 63;
    int wr = w >> 1, wc = w & 1;
    int nkt = Kk >> 5;

    // staging geometry: wave w owns LDS chunks [w*128, w*128+128)
    int q0 = w * 128;
    int qa0 = q0 + lane, qa1 = q0 + 64 + lane;
    int r0s = qa0 >> 2, c0s = (qa0 & 3) ^ ((r0s >> 1) & 3);
    int r1s = qa1 >> 2, c1s = (qa1 & 3) ^ ((r1s >> 1) & 3);
    int ar0 = m0 + r0s; if (ar0 > Mm - 1) ar0 = Mm - 1;
    int ar1 = m0 + r1s; if (ar1 > Mm - 1) ar1 = Mm - 1;
    int br0 = n0 + r0s; if (br0 > Nn - 1) br0 = Nn - 1;
    int br1 = n0 + r1s; if (br1 > Nn - 1) br1 = Nn - 1;
    const us* pa0 = A + (ll)ar0 * lda + c0s * 8;
    const us* pa1 = A + (ll)ar1 * lda + c1s * 8;
    const us* pb0 = Bt + (ll)br0 * ldb + c0s * 8;
    const us* pb1 = Bt + (ll)br1 * ldb + c1s * 8;
    int la0o = q0 * 8, la1o = (q0 + 64) * 8;

    int l15 = lane & 15, l4 = lane >> 4;
    int aoff[4], boff[4];
#pragma unroll
    for (int f = 0; f < 4; f++) {
        int row = wr * 64 + f * 16 + l15;
        aoff[f] = row * 32 + ((l4 ^ ((row >> 1) & 3)) << 3);
        int col = wc * 64 + f * 16 + l15;
        boff[f] = col * 32 + ((l4 ^ ((col >> 1) & 3)) << 3);
    }

    f32x4 acc[4][4];
#pragma unroll
    for (int i = 0; i < 4; i++)
#pragma unroll
        for (int j = 0; j < 4; j++) acc[i][j] = (f32x4){0.f, 0.f, 0.f, 0.f};

    auto stage = [&](int buf, int kt) {
        int k0 = kt << 5;
        gload16(pa0 + k0, &As[buf][la0o]);
        gload16(pa1 + k0, &As[buf][la1o]);
        gload16(pb0 + k0, &Bs[buf][la0o]);
        gload16(pb1 + k0, &Bs[buf][la1o]);
    };

    stage(0, 0);
    for (int kt = 0; kt < nkt; ++kt) {
        int cur = kt & 1;
        if (kt + 1 < nkt) {
            stage(cur ^ 1, kt + 1);
            asm volatile("s_waitcnt vmcnt(4)" ::: "memory");   // own cur-buf loads done
        } else {
            asm volatile("s_waitcnt vmcnt(0)" ::: "memory");
        }
        __builtin_amdgcn_s_barrier();                          // all waves staged
        asm volatile("" ::: "memory");
        bf16x8 af[4], bfr[4];
#pragma unroll
        for (int f = 0; f < 4; f++) af[f] = *(const bf16x8*)&As[cur][aoff[f]];
#pragma unroll
        for (int f = 0; f < 4; f++) bfr[f] = *(const bf16x8*)&Bs[cur][boff[f]];
#pragma unroll
        for (int i = 0; i < 4; i++)
#pragma unroll
            for (int j = 0; j < 4; j++)
                acc[i][j] = __builtin_amdgcn_mfma_f32_16x16x32_bf16(af[i], bfr[j], acc[i][j], 0, 0, 0);
        asm volatile("" ::: "memory");
        __builtin_amdgcn_s_barrier();                          // reads done before next stage overwrites
        asm volatile("" ::: "memory");
    }

#pragma unroll
    for (int fm = 0; fm < 4; fm++) {
        int rb = m0 + wr * 64 + fm * 16 + l4 * 4;
#pragma unroll
        for (int fn = 0; fn < 4; fn++) {
            int c = n0 + wc * 64 + fn * 16 + l15;
            if (c >= Nstore) continue;
#pragma unroll
            for (int i = 0; i < 4; i++) {
                int r = rb + i - rSub;
                if (r < 0 || r >= Mstore) continue;
                float v = acc[fm][fn][i];
                if (EPI == 2) {
                    float o = v + bias[c] + addp[(ll)r * ldadd + c];
                    C[(ll)r * ldc + c] = o;
                    C2[(ll)r * ldc + c] = f2b(o);
                } else if (EPI == 3) {
                    int part = c >> 9, hh = (c >> 6) & 7, dd = c & 63;
                    float o = (part == 0) ? v * 0.125f : v;
                    C2[((ll)(part * 8 + hh) * NPAD + r) * 64 + dd] = f2b(o);
                } else if (EPI == 10) {
                    C2[(ll)r * ldc + c] = f2b(v + bias[c]);
                } else if (EPI == 11) {
                    float xl = alphap[r] * (v + bias[c]);
                    float enc = C[(ll)r * ldc + c];
                    float sg = 1.0f / (1.0f + __expf(xl));
                    float sw = sg * sg;
                    C[(ll)r * ldc + c] = xl * 2.0f * sw + 2.0f * enc * (1.0f - sw);
                }
            }
        }
    }
}

// ---------------------------------------------------------------------------
// Persistent fused pinv: 6 Newton-Schulz iterations x 4 GEMM stages, 32 blocks
// (8 heads x 2x2 tiles), device-scope spin barrier between stages.
__global__ __launch_bounds__(256)
void pinv_fused(const us* __restrict__ XN, us* __restrict__ ZN, us* __restrict__ ZT,
                us* __restrict__ ZN2, us* __restrict__ ZT2,
                us* __restrict__ XZN, us* __restrict__ W1T, us* __restrict__ W2T,
                us* __restrict__ W3T, int* __restrict__ bar)
{
    __shared__ us As[128 * 32];
    __shared__ us Bs[128 * 32];
    int z = blockIdx.x;
    int h = z >> 2, tt = z & 3;
    int m0 = (tt >> 1) * 128, n0 = (tt & 1) * 128;
    int tid = threadIdx.x, w = tid >> 6, lane = tid & 63;
    int wr = w >> 1, wc = w & 1;
    int l15 = lane & 15, l4 = lane >> 4;
    ll hb = (ll)h << 16;

    int q0 = w * 128;
    int qa0 = q0 + lane, qa1 = q0 + 64 + lane;
    int r0s = qa0 >> 2, c0s = (qa0 & 3) ^ ((r0s >> 1) & 3);
    int r1s = qa1 >> 2, c1s = (qa1 & 3) ^ ((r1s >> 1) & 3);
    int la0o = q0 * 8, la1o = (q0 + 64) * 8;
    int aoff[4], boff[4];
#pragma unroll
    for (int f = 0; f < 4; f++) {
        int row = wr * 64 + f * 16 + l15;
        aoff[f] = row * 32 + ((l4 ^ ((row >> 1) & 3)) << 3);
        int col = wc * 64 + f * 16 + l15;
        boff[f] = col * 32 + ((l4 ^ ((col >> 1) & 3)) << 3);
    }

    auto gemm128 = [&](const us* Ah, const us* Bth, f32x4 (&acc)[4][4]) {
#pragma unroll
        for (int i = 0; i < 4; i++)
#pragma unroll
            for (int j = 0; j < 4; j++) acc[i][j] = (f32x4){0.f, 0.f, 0.f, 0.f};
        const us* pa0 = Ah + (m0 + r0s) * 256 + c0s * 8;
        const us* pa1 = Ah + (m0 + r1s) * 256 + c1s * 8;
        const us* pb0 = Bth + (n0 + r0s) * 256 + c0s * 8;
        const us* pb1 = Bth + (n0 + r1s) * 256 + c1s * 8;
        for (int kt = 0; kt < 8; ++kt) {
            int k0 = kt << 5;
            gload16(pa0 + k0, &As[la0o]);
            gload16(pa1 + k0, &As[la1o]);
            gload16(pb0 + k0, &Bs[la0o]);
            gload16(pb1 + k0, &Bs[la1o]);
            __syncthreads();
            bf16x8 af[4], bfr[4];
#pragma unroll
            for (int f = 0; f < 4; f++) af[f] = *(const bf16x8*)&As[aoff[f]];
#pragma unroll
            for (int f = 0; f < 4; f++) bfr[f] = *(const bf16x8*)&Bs[boff[f]];
#pragma unroll
            for (int i = 0; i < 4; i++)
#pragma unroll
                for (int j = 0; j < 4; j++)
                    acc[i][j] = __builtin_amdgcn_mfma_f32_16x16x32_bf16(af[i], bfr[j], acc[i][j], 0, 0, 0);
            __syncthreads();
        }
    };

    int epoch = 0;
    auto gbar = [&]() {
        __syncthreads();
        __threadfence();          // release: writes visible device-wide
        ++epoch;
        if (tid == 0) {
            atomicAdd(bar, 1);
            while (atomicAdd(bar, 0) < epoch * PINV_BLOCKS) __builtin_amdgcn_s_sleep(16);
        }
        __syncthreads();
        __threadfence();          // acquire: drop stale cached lines
    };

    us* znc = ZN; us* ztc = ZT; us* znn = ZN2; us* ztn = ZT2;
    f32x4 acc[4][4];
    for (int it = 0; it < 6; ++it) {
        // stage A: XZ = X @ Z ; W1T = (7I - XZ)^T
        gemm128(XN + hb, ztc + hb, acc);
#pragma unroll
        for (int fm = 0; fm < 4; fm++)
#pragma unroll
            for (int fn = 0; fn < 4; fn++)
#pragma unroll
                for (int i = 0; i < 4; i++) {
                    int r = m0 + wr * 64 + fm * 16 + l4 * 4 + i;
                    int c = n0 + wc * 64 + fn * 16 + l15;
                    float v = acc[fm][fn][i];
                    XZN[hb + (ll)r * 256 + c] = f2b(v);
                    W1T[hb + (ll)c * 256 + r] = f2b(((r == c) ? 7.0f : 0.0f) - v);
                }
        gbar();
        // stage B: W2T = (15I - XZ @ W1)^T
        gemm128(XZN + hb, W1T + hb, acc);
#pragma unroll
        for (int fm = 0; fm < 4; fm++)
#pragma unroll
            for (int fn = 0; fn < 4; fn++)
#pragma unroll
                for (int i = 0; i < 4; i++) {
                    int r = m0 + wr * 64 + fm * 16 + l4 * 4 + i;
                    int c = n0 + wc * 64 + fn * 16 + l15;
                    W2T[hb + (ll)c * 256 + r] = f2b(((r == c) ? 15.0f : 0.0f) - acc[fm][fn][i]);
                }
        gbar();
        // stage C: W3T = (13I - XZ @ W2)^T
        gemm128(XZN + hb, W2T + hb, acc);
#pragma unroll
        for (int fm = 0; fm < 4; fm++)
#pragma unroll
            for (int fn = 0; fn < 4; fn++)
#pragma unroll
                for (int i = 0; i < 4; i++) {
                    int r = m0 + wr * 64 + fm * 16 + l4 * 4 + i;
                    int c = n0 + wc * 64 + fn * 16 + l15;
                    W3T[hb + (ll)c * 256 + r] = f2b(((r == c) ? 13.0f : 0.0f) - acc[fm][fn][i]);
                }
        gbar();
        // stage D: Znew = 0.25 * Z @ W3  (normal + transposed stores)
        gemm128(znc + hb, W3T + hb, acc);
#pragma unroll
        for (int fm = 0; fm < 4; fm++)
#pragma unroll
            for (int fn = 0; fn < 4; fn++)
#pragma unroll
                for (int i = 0; i < 4; i++) {
                    int r = m0 + wr * 64 + fm * 16 + l4 * 4 + i;
                    int c = n0 + wc * 64 + fn * 16 + l15;
                    us q = f2b(0.25f * acc[fm][fn][i]);
                    znn[hb + (ll)r * 256 + c] = q;
                    ztn[hb + (ll)c * 256 + r] = q;
                }
        gbar();
        us* t;
        t = znc; znc = znn; znn = t;
        t = ztc; ztc = ztn; ztn = t;
    }
}

// ---------------------------------------------------------------------------
// fp32 GEMM (attn2 / pinv refinement / PW). TB=1: C=A@B^T. EPI 0: C=alpha*acc;
// EPI 4: C = diagv*I - acc.
#define BM 128
#define BN 64
#define BK 16
template<int TB, int EPI>
__global__ __launch_bounds__(256)
void gemm_k(const float* __restrict__ A, const float* __restrict__ B, float* __restrict__ C,
            int Mm, int Nn, int Kk, int lda, int ldb, int ldc,
            ll sA, ll sB, ll sC, float alpha, float diagv)
{
    __shared__ float As[BK][132];
    __shared__ float Bs[BK][68];
    int batch = blockIdx.z;
    A += (ll)batch * sA; B += (ll)batch * sB; C += (ll)batch * sC;
    int m0 = blockIdx.y * BM, n0 = blockIdx.x * BN;
    int tid = threadIdx.x, tx = tid & 15, ty = tid >> 4;
    int arow_t = tid >> 1, akh = (tid & 1) * 8;
    bool avalid = (m0 + arow_t < Mm);
    const float* Arow = A + (ll)(m0 + arow_t) * lda;
    float acc[8][4];
#pragma unroll
    for (int i = 0; i < 8; i++)
#pragma unroll
        for (int j = 0; j < 4; j++) acc[i][j] = 0.f;
    for (int kt = 0; kt < Kk / BK; ++kt) {
        int k0 = kt * BK;
        float4 av0 = make_float4(0, 0, 0, 0), av1 = av0;
        if (avalid) {
            av0 = *(const float4*)(Arow + k0 + akh);
            av1 = *(const float4*)(Arow + k0 + akh + 4);
        }
        float4 bv;
        if (TB == 0) bv = *(const float4*)(B + (ll)(k0 + (tid >> 4)) * ldb + n0 + (tid & 15) * 4);
        else         bv = *(const float4*)(B + (ll)(n0 + (tid >> 2)) * ldb + k0 + (tid & 3) * 4);
        __syncthreads();
        As[akh + 0][arow_t] = av0.x; As[akh + 1][arow_t] = av0.y;
        As[akh + 2][arow_t] = av0.z; As[akh + 3][arow_t] = av0.w;
        As[akh + 4][arow_t] = av1.x; As[akh + 5][arow_t] = av1.y;
        As[akh + 6][arow_t] = av1.z; As[akh + 7][arow_t] = av1.w;
        if (TB == 0) *(float4*)&Bs[tid >> 4][(tid & 15) * 4] = bv;
        else {
            int bk4 = (tid & 3) * 4, bn = tid >> 2;
            Bs[bk4 + 0][bn] = bv.x; Bs[bk4 + 1][bn] = bv.y;
            Bs[bk4 + 2][bn] = bv.z; Bs[bk4 + 3][bn] = bv.w;
        }
        __syncthreads();
#pragma unroll
        for (int kk = 0; kk < BK; kk++) {
            float ar[8], br[4];
            *(float4*)&ar[0] = *(const float4*)&As[kk][ty * 8];
            *(float4*)&ar[4] = *(const float4*)&As[kk][ty * 8 + 4];
            *(float4*)&br[0] = *(const float4*)&Bs[kk][tx * 4];
#pragma unroll
            for (int i = 0; i < 8; i++)
#pragma unroll
                for (int j = 0; j < 4; j++) acc[i][j] = fmaf(ar[i], br[j], acc[i][j]);
        }
    }
    int c0 = n0 + tx * 4;
#pragma unroll
    for (int i = 0; i < 8; i++) {
        int r = m0 + ty * 8 + i;
        if (r >= Mm) continue;
#pragma unroll
        for (int j = 0; j < 4; j++) {
            int c = c0 + j;
            if (c >= Nn) continue;
            float v = acc[i][j];
            if (EPI == 0) C[(ll)r * ldc + c] = alpha * v;
            else if (EPI == 4) C[(ll)r * ldc + c] = ((r == c) ? diagv : 0.f) - v;
        }
    }
}

// ---------------------------------------------------------------------------
// Fused attn3: KVpartial[h,chunk] = sum_{seq in chunk} exp(QL@K^T) V, Zpartial rowsums
__global__ __launch_bounds__(256)
void attn3_fused(const us* __restrict__ QLB, const us* __restrict__ Kh,
                 const us* __restrict__ VT, float* __restrict__ KVP,
                 float* __restrict__ ZP)
{
    __shared__ us sP[4][4096];
    int h = blockIdx.y, c0 = blockIdx.x * 512;
    int w = threadIdx.x >> 6, lane = threadIdx.x & 63;
    int l15 = lane & 15, l4 = lane >> 4;
    const us* QLh = QLB + (ll)h * 16384;
    const us* Khh = Kh + (ll)h * NPAD * 64;
    const us* VTh = VT + (ll)h * 64 * NPAD;
    us* P = sP[w];

    bf16x8 aq[4][2];
#pragma unroll
    for (int fm = 0; fm < 4; fm++)
#pragma unroll
        for (int ks = 0; ks < 2; ks++)
            aq[fm][ks] = *(const bf16x8*)&QLh[(w * 64 + fm * 16 + l15) * 64 + l4 * 8 + ks * 32];

    f32x4 acc2[4][4];
    float zacc[4][4];
#pragma unroll
    for (int a = 0; a < 4; a++)
#pragma unroll
        for (int b = 0; b < 4; b++) { acc2[a][b] = (f32x4){0.f,0.f,0.f,0.f}; zacc[a][b] = 0.f; }

    for (int sub = 0; sub < 8; ++sub) {
        int s0 = c0 + sub * 64;
        f32x4 s[4][4];
#pragma unroll
        for (int a = 0; a < 4; a++)
#pragma unroll
            for (int b = 0; b < 4; b++) s[a][b] = (f32x4){0.f,0.f,0.f,0.f};
#pragma unroll
        for (int ks = 0; ks < 2; ks++) {
            bf16x8 bk[4];
#pragma unroll
            for (int fn = 0; fn < 4; fn++)
                bk[fn] = *(const bf16x8*)&Khh[(ll)(s0 + fn * 16 + l15) * 64 + l4 * 8 + ks * 32];
#pragma unroll
            for (int fm = 0; fm < 4; fm++)
#pragma unroll
                for (int fn = 0; fn < 4; fn++)
                    s[fm][fn] = __builtin_amdgcn_mfma_f32_16x16x32_bf16(aq[fm][ks], bk[fn], s[fm][fn], 0, 0, 0);
        }
#pragma unroll
        for (int fm = 0; fm < 4; fm++)
#pragma unroll
            for (int i = 0; i < 4; i++) {
                int row = fm * 16 + l4 * 4 + i;
#pragma unroll
                for (int fn = 0; fn < 4; fn++) {
                    float e = __expf(s[fm][fn][i]);
                    zacc[fm][i] += e;
                    int col = fn * 16 + l15;
                    P[row * 64 + (((col >> 3) ^ (row & 7)) << 3) + (col & 7)] = f2b(e);
                }
            }
#pragma unroll
        for (int ks = 0; ks < 2; ks++) {
            bf16x8 ap[4], bv[4];
#pragma unroll
            for (int fm = 0; fm < 4; fm++) {
                int row = fm * 16 + l15;
                int ch = (l4 + ks * 4) ^ (row & 7);
                ap[fm] = *(const bf16x8*)&P[row * 64 + ch * 8];
            }
#pragma unroll
            for (int fn = 0; fn < 4; fn++)
                bv[fn] = *(const bf16x8*)&VTh[(ll)(fn * 16 + l15) * NPAD + s0 + l4 * 8 + ks * 32];
#pragma unroll
            for (int fm = 0; fm < 4; fm++)
#pragma unroll
                for (int fn = 0; fn < 4; fn++)
                    acc2[fm][fn] = __builtin_amdgcn_mfma_f32_16x16x32_bf16(ap[fm], bv[fn], acc2[fm][fn], 0, 0, 0);
        }
    }
    float* KP = KVP + ((ll)h * NCHUNK + blockIdx.x) * 16384;
#pragma unroll
    for (int fm = 0; fm < 4; fm++)
#pragma unroll
        for (int fn = 0; fn < 4; fn++)
#pragma unroll
            for (int i = 0; i < 4; i++)
                KP[(w * 64 + fm * 16 + l4 * 4 + i) * 64 + fn * 16 + l15] = acc2[fm][fn][i];
#pragma unroll
    for (int fm = 0; fm < 4; fm++)
#pragma unroll
        for (int i = 0; i < 4; i++) {
            float zz = zacc[fm][i];
            zz += __shfl_xor(zz, 1, 64); zz += __shfl_xor(zz, 2, 64);
            zz += __shfl_xor(zz, 4, 64); zz += __shfl_xor(zz, 8, 64);
            if (l15 == 0)
                ZP[((ll)h * NCHUNK + blockIdx.x) * 256 + w * 64 + fm * 16 + l4 * 4 + i] = zz;
        }
}

__global__ void kv_reduce2(const float* __restrict__ KVP, const float* __restrict__ ZP,
                           float* __restrict__ KV)
{
    int e = blockIdx.x * 256 + threadIdx.x;   // < 131072
    int h = e >> 14, r = (e >> 6) & 255;
    float s = 0.f, z = 0.f;
    for (int c = 0; c < NCHUNK; ++c) {
        s += KVP[((ll)h * NCHUNK + c) * 16384 + (e & 16383)];
        z += ZP[((ll)h * NCHUNK + c) * 256 + r];
    }
    KV[e] = s / z;
}

// ---------------------------------------------------------------------------
// Fused attn1: ATTP[r, h*64+d] = bf16( softmax(Q@KL^T) @ PW + ATT[r, h*64+d] )
__global__ __launch_bounds__(256)
void attn1_fused(const us* __restrict__ Qh, const us* __restrict__ KLB,
                 const us* __restrict__ PWT, const float* __restrict__ ATT,
                 us* __restrict__ ATTP)
{
    __shared__ us sP[4][4096];
    int h = blockIdx.y, r0 = blockIdx.x * 128;
    int w = threadIdx.x >> 6, lane = threadIdx.x & 63;
    int l15 = lane & 15, l4 = lane >> 4;
    const us* Qhh = Qh + (ll)h * NPAD * 64;
    const us* KLh = KLB + (ll)h * 16384;
    const us* PWh = PWT + (ll)h * 16384;
    us* P = sP[w];

    bf16x8 aq[2][2];
#pragma unroll
    for (int fm = 0; fm < 2; fm++)
#pragma unroll
        for (int ks = 0; ks < 2; ks++) {
            int r = r0 + w * 32 + fm * 16 + l15;
            if (r > NSEQ - 1) r = NSEQ - 1;
            aq[fm][ks] = *(const bf16x8*)&Qhh[(ll)(r + FPAD) * 64 + l4 * 8 + ks * 32];
        }

    f32x4 s[2][16];
#pragma unroll
    for (int a = 0; a < 2; a++)
#pragma unroll
        for (int b = 0; b < 16; b++) s[a][b] = (f32x4){0.f,0.f,0.f,0.f};
#pragma unroll
    for (int ks = 0; ks < 2; ks++)
#pragma unroll
        for (int fn = 0; fn < 16; fn++) {
            bf16x8 bk = *(const bf16x8*)&KLh[(fn * 16 + l15) * 64 + l4 * 8 + ks * 32];
            s[0][fn] = __builtin_amdgcn_mfma_f32_16x16x32_bf16(aq[0][ks], bk, s[0][fn], 0, 0, 0);
            s[1][fn] = __builtin_amdgcn_mfma_f32_16x16x32_bf16(aq[1][ks], bk, s[1][fn], 0, 0, 0);
        }
#pragma unroll
    for (int fm = 0; fm < 2; fm++)
#pragma unroll
        for (int i = 0; i < 4; i++) {
            float m = s[fm][0][i];
#pragma unroll
            for (int fn = 1; fn < 16; fn++) m = fmaxf(m, s[fm][fn][i]);
            m = fmaxf(m, __shfl_xor(m, 1, 64)); m = fmaxf(m, __shfl_xor(m, 2, 64));
            m = fmaxf(m, __shfl_xor(m, 4, 64)); m = fmaxf(m, __shfl_xor(m, 8, 64));
            float sum = 0.f;
#pragma unroll
            for (int fn = 0; fn < 16; fn++) {
                float e = __expf(s[fm][fn][i] - m);
                s[fm][fn][i] = e; sum += e;
            }
            sum += __shfl_xor(sum, 1, 64); sum += __shfl_xor(sum, 2, 64);
            sum += __shfl_xor(sum, 4, 64); sum += __shfl_xor(sum, 8, 64);
            float rinv = 1.0f / sum;
#pragma unroll
            for (int fn = 0; fn < 16; fn++) s[fm][fn][i] *= rinv;
        }
    f32x4 acc2[2][4];
#pragma unroll
    for (int a = 0; a < 2; a++)
#pragma unroll
        for (int b = 0; b < 4; b++) acc2[a][b] = (f32x4){0.f,0.f,0.f,0.f};
#pragma unroll
    for (int half = 0; half < 2; ++half) {
#pragma unroll
        for (int fm = 0; fm < 2; fm++)
#pragma unroll
            for (int i = 0; i < 4; i++) {
                int row = fm * 16 + l4 * 4 + i;
#pragma unroll
                for (int fh = 0; fh < 8; fh++) {
                    int col = fh * 16 + l15;
                    P[row * 128 + (((col >> 3) ^ (row & 7)) << 3) + (col & 7)] =
                        f2b(s[fm][half * 8 + fh][i]);
                }
            }
#pragma unroll
        for (int ks = 0; ks < 4; ks++) {
            bf16x8 ap[2];
#pragma unroll
            for (int fm = 0; fm < 2; fm++) {
                int row = fm * 16 + l15;
                int ch = (l4 + ks * 4) ^ (row & 7);
                ap[fm] = *(const bf16x8*)&P[row * 128 + ch * 8];
            }
#pragma unroll
            for (int fn = 0; fn < 4; fn++) {
                bf16x8 bp = *(const bf16x8*)&PWh[(ll)(fn * 16 + l15) * 256 + half * 128 + l4 * 8 + ks * 32];
                acc2[0][fn] = __builtin_amdgcn_mfma_f32_16x16x32_bf16(ap[0], bp, acc2[0][fn], 0, 0, 0);
                acc2[1][fn] = __builtin_amdgcn_mfma_f32_16x16x32_bf16(ap[1], bp, acc2[1][fn], 0, 0, 0);
            }
        }
    }
#pragma unroll
    for (int fm = 0; fm < 2; fm++)
#pragma unroll
        for (int fn = 0; fn < 4; fn++)
#pragma unroll
            for (int i = 0; i < 4; i++) {
                int r = r0 + w * 32 + fm * 16 + l4 * 4 + i;
                if (r < NSEQ) {
                    int d = fn * 16 + l15;
                    float a = acc2[fm][fn][i] + ATT[(ll)r * 512 + h * 64 + d];
                    ATTP[(ll)r * 512 + h * 64 + d] = f2b(a);
                }
            }
}

// ---------------------------------------------------------------------------
__global__ void trans_f2b(const float* __restrict__ in, us* __restrict__ out,
                          int R, int Cc, ll sI, ll sO)
{
    __shared__ float tile[32][33];
    const float* inp = in + (ll)blockIdx.z * sI;
    us* outp = out + (ll)blockIdx.z * sO;
    int r0 = blockIdx.y * 32, c0 = blockIdx.x * 32;
    int tx = threadIdx.x & 31, ty = threadIdx.x >> 5;
#pragma unroll
    for (int i = 0; i < 4; i++) {
        int r = r0 + ty + i * 8, c = c0 + tx;
        tile[ty + i * 8][tx] = (r < R && c < Cc) ? inp[(ll)r * Cc + c] : 0.f;
    }
    __syncthreads();
#pragma unroll
    for (int i = 0; i < 4; i++) {
        int c = c0 + ty + i * 8, r = r0 + tx;
        if (c < Cc && r < R) outp[(ll)c * R + r] = f2b(tile[tx][ty + i * 8]);
    }
}

__global__ void trans_b2b(const us* __restrict__ in, us* __restrict__ out,
                          int R, int Cc, ll sI, ll sO)
{
    __shared__ us tile[32][34];
    const us* inp = in + (ll)blockIdx.z * sI;
    us* outp = out + (ll)blockIdx.z * sO;
    int r0 = blockIdx.y * 32, c0 = blockIdx.x * 32;
    int tx = threadIdx.x & 31, ty = threadIdx.x >> 5;
#pragma unroll
    for (int i = 0; i < 4; i++) {
        int r = r0 + ty + i * 8, c = c0 + tx;
        tile[ty + i * 8][tx] = (r < R && c < Cc) ? inp[(ll)r * Cc + c] : (us)0;
    }
    __syncthreads();
#pragma unroll
    for (int i = 0; i < 4; i++) {
        int c = c0 + ty + i * 8, r = r0 + tx;
        if (c < Cc && r < R) outp[(ll)c * R + r] = tile[tx][ty + i * 8];
    }
}

__global__ void dense_pad_b(const float* __restrict__ x, us* __restrict__ o)
{
    ll e4 = ((ll)blockIdx.x * 256 + threadIdx.x) * 4;
    int r = (int)(e4 >> 10), c = (int)(e4 & 1023);
    ushort4 u;
    if (r < FPAD) { u.x = u.y = u.z = u.w = 0; }
    else {
        float4 v = *(const float4*)&x[(ll)(r - FPAD) * 1024 + c];
        u.x = f2b(v.x); u.y = f2b(v.y); u.z = f2b(v.z); u.w = f2b(v.w);
    }
    *(ushort4*)&o[e4] = u;
}

__global__ void f2b_vec(const float* __restrict__ in, us* __restrict__ out, int n)
{
    int i = blockIdx.x * 256 + threadIdx.x;
    if (i < n) out[i] = f2b(in[i]);
}

__global__ void concat_bias(const float* __restrict__ a, const float* __restrict__ b,
                            float* __restrict__ o)
{
    int t = threadIdx.x;
    o[t] = a[t]; o[256 + t] = b[t];
}

__global__ void landmark_mean_b(const us* __restrict__ src, float* __restrict__ dst)
{
    int b = blockIdx.x;
    int h = b >> 8, jm = b & 255;
    int d = threadIdx.x;
    const us* p = src + ((ll)h * NPAD + (ll)jm * LCHUNK) * DHEAD + d;
    float s = 0.f;
    for (int jl = 0; jl < LCHUNK; ++jl) s += b2f(p[jl * DHEAD]);
    dst[((h << 8) + jm) * DHEAD + d] = s * (1.0f / LCHUNK);
}

__global__ void rowsoftmax256(float* __restrict__ X)
{
    __shared__ float red[256];
    float* p = X + (ll)blockIdx.x * 256;
    int t = threadIdx.x;
    float v = p[t];
    red[t] = v; __syncthreads();
    for (int s = 128; s > 0; s >>= 1) { if (t < s) red[t] = fmaxf(red[t], red[t + s]); __syncthreads(); }
    float m = red[0]; __syncthreads();
    float e = expf(v - m);
    red[t] = e; __syncthreads();
    for (int s = 128; s > 0; s >>= 1) { if (t < s) red[t] += red[t + s]; __syncthreads(); }
    p[t] = e / red[0];
}

__global__ void colrow_max(const float* __restrict__ A2, float* __restrict__ hm)
{
    __shared__ float red[256];
    int h = blockIdx.x, t = threadIdx.x;
    const float* X = A2 + (ll)h * LM * LM;
    float cs = 0.f;
    for (int i = 0; i < LM; ++i) cs += X[i * LM + t];
    red[t] = cs; __syncthreads();
    for (int s = 128; s > 0; s >>= 1) { if (t < s) red[t] = fmaxf(red[t], red[t + s]); __syncthreads(); }
    if (t == 0) hm[h] = red[0];
    __syncthreads();
    float rs = 0.f;
    const float* Xr = X + (ll)t * LM;
    for (int j = 0; j < LM; ++j) rs += Xr[j];
    red[t] = rs; __syncthreads();
    for (int s = 128; s > 0; s >>= 1) { if (t < s) red[t] = fmaxf(red[t], red[t + s]); __syncthreads(); }
    if (t == 0) hm[8 + h] = red[0];
}

__global__ void denom_fin(const float* __restrict__ hm, float* __restrict__ scal)
{
    float cm = hm[0], rm = hm[8];
    for (int h = 1; h < 8; ++h) { cm = fmaxf(cm, hm[h]); rm = fmaxf(rm, hm[8 + h]); }
    scal[0] = 1.0f / (cm * rm);
}

__global__ void pinv_init(const float* __restrict__ A2, const float* __restrict__ scal,
                          us* __restrict__ XN, us* __restrict__ ZN, us* __restrict__ ZT)
{
    ll e = (ll)blockIdx.x * 256 + threadIdx.x;
    int h = (int)(e >> 16), r = (int)(e >> 8) & 255, c = (int)e & 255;
    float v = A2[e];
    XN[e] = f2b(v);
    float vs = v * scal[0];
    ZT[e] = f2b(vs);
    ZN[((ll)h << 16) + ((ll)c << 8) + r] = f2b(vs);
}

__global__ void zwiden(const us* __restrict__ zn, float* __restrict__ zf)
{
    ll e = (ll)blockIdx.x * 256 + threadIdx.x;
    zf[e] = b2f(zn[e]);
}

__global__ void seven_i_minus(const float* __restrict__ XZ, float* __restrict__ Wo)
{
    ll e = (ll)blockIdx.x * 256 + threadIdx.x;
    int r = (int)(e >> 8) & 255; int c = (int)e & 255;
    Wo[e] = ((r == c) ? 7.0f : 0.0f) - XZ[e];
}

__global__ void conv_res(const us* __restrict__ V, const float* __restrict__ cw,
                         float* __restrict__ ATT)
{
    int h = blockIdx.y;
    int i = blockIdx.x * 4 + (threadIdx.x >> 6);
    int d = threadIdx.x & 63;
    if (i >= NSEQ) return;
    const us* Vh = V + (ll)h * NPAD * DHEAD;
    int n0 = FPAD + i - 16;
    float s = 0.f;
#pragma unroll
    for (int kk = 0; kk < 33; ++kk) {
        int n = n0 + kk;
        if (n < NPAD) s += cw[h * 33 + kk] * b2f(Vh[(ll)n * DHEAD + d]);
    }
    ATT[(ll)i * INNER + h * DHEAD + d] = s;
}

__global__ void zero_f32(float* __restrict__ p, int n)
{
    int i = blockIdx.x * 256 + threadIdx.x;
    if (i < n) p[i] = 0.f;
}

__global__ void edge_scores_b(const int* __restrict__ ei, const float* __restrict__ adj,
                              const us* __restrict__ qk2, float* __restrict__ Araw, int E)
{
    int gw = (blockIdx.x * 256 + threadIdx.x) >> 6;
    int lane = threadIdx.x & 63;
    if (gw >= E) return;
    int src = ei[gw], dst = ei[E + gw];
    const uint32* qp = (const uint32*)(qk2 + (ll)src * 512);
    const uint32* kp = (const uint32*)(qk2 + (ll)dst * 512 + 256);
    float acc = 0.f;
#pragma unroll
    for (int t = 0; t < 2; t++) {
        uint32 qu = qp[lane + t * 64], ku = kp[lane + t * 64];
        acc += b2f((us)(qu & 0xffff)) * b2f((us)(ku & 0xffff));
        acc += b2f((us)(qu >> 16)) * b2f((us)(ku >> 16));
    }
#pragma unroll
    for (int m = 32; m >= 1; m >>= 1) acc += __shfl_xor(acc, m, 64);
    if (lane == 0) atomicAdd(Araw + src, acc * adj[gw] * 0.0625f);
}

__global__ void softmax30k_stats(const float* __restrict__ A, float* __restrict__ scal)
{
    __shared__ float red[1024];
    int t = threadIdx.x;
    float m = -3.0e38f;
    for (int i = t; i < NSEQ; i += 1024) m = fmaxf(m, A[i]);
    red[t] = m; __syncthreads();
    for (int s = 512; s > 0; s >>= 1) { if (t < s) red[t] = fmaxf(red[t], red[t + s]); __syncthreads(); }
    m = red[0]; __syncthreads();
    float sum = 0.f;
    for (int i = t; i < NSEQ; i += 1024) sum += expf(A[i] - m);
    red[t] = sum; __syncthreads();
    for (int s = 512; s > 0; s >>= 1) { if (t < s) red[t] += red[t + s]; __syncthreads(); }
    if (t == 0) { scal[1] = m; scal[2] = red[0]; }
}

__global__ void alpha_kernel(const float* __restrict__ A, const float* __restrict__ scal,
                             float* __restrict__ alpha)
{
    int i = blockIdx.x * 256 + threadIdx.x;
    if (i < NSEQ) alpha[i] = expf(A[i] - scal[1]) / scal[2];
}

// ---------------------------------------------------------------------------
extern "C" void kernel_launch(void* const* d_in, const int* in_sizes, int n_in,
                              void* d_out, int out_size, void* d_ws, size_t ws_size,
                              hipStream_t stream)
{
    const float* dense  = (const float*)d_in[0];
    const int*   ei     = (const int*)d_in[1];
    const float* adj    = (const float*)d_in[2];
    const float* qkv_w  = (const float*)d_in[3];
    const float* out_w  = (const float*)d_in[4];
    const float* out_b  = (const float*)d_in[5];
    const float* conv_w = (const float*)d_in[6];
    const float* wq_w   = (const float*)d_in[7];
    const float* wq_b   = (const float*)d_in[8];
    const float* wk_w   = (const float*)d_in[9];
    const float* wk_b   = (const float*)d_in[10];
    const float* wv_w   = (const float*)d_in[11];
    const float* wv_b   = (const float*)d_in[12];
    int E = in_sizes[2];

    char* w = (char*)d_ws;
    auto alloc = [&](ll bytes) { char* p = w; w += (bytes + 255) & ~(ll)255; return p; };

    us*    DENSEP = (us*)alloc((ll)NPAD * 1024 * 2);
    us*    QKVH   = (us*)alloc((ll)3 * 8 * NPAD * 64 * 2);
    us*    ENCB   = QKVH;                         // alias: QKVH dead before out-proj writes ENCB
    us*    Qh = QKVH, *Kh = QKVH + (ll)8 * NPAD * 64, *Vh = QKVH + (ll)16 * NPAD * 64;
    us*    VT     = (us*)alloc((ll)8 * 64 * NPAD * 2);
    us*    QKVWT  = (us*)alloc((ll)1536 * 1024 * 2);
    us*    OUTWT  = (us*)alloc((ll)1024 * 512 * 2);
    us*    WQKT   = (us*)alloc((ll)512 * 1024 * 2);
    us*    WVT    = (us*)alloc((ll)1024 * 1024 * 2);
    float* WQKB   = (float*)alloc(512 * 4);
    float* QL     = (float*)alloc((ll)8 * 256 * 64 * 4);
    float* KL     = (float*)alloc((ll)8 * 256 * 64 * 4);
    us*    QLB    = (us*)alloc((ll)8 * 256 * 64 * 2);
    us*    KLB    = (us*)alloc((ll)8 * 256 * 64 * 2);
    float* A2     = (float*)alloc((ll)8 * 65536 * 4);
    us*    XN     = (us*)alloc((ll)8 * 65536 * 2);
    us*    ZN     = (us*)alloc((ll)8 * 65536 * 2);
    us*    ZT     = (us*)alloc((ll)8 * 65536 * 2);
    us*    ZN2    = (us*)alloc((ll)8 * 65536 * 2);
    us*    ZT2    = (us*)alloc((ll)8 * 65536 * 2);
    us*    XZN    = (us*)alloc((ll)8 * 65536 * 2);
    us*    W1T    = (us*)alloc((ll)8 * 65536 * 2);
    us*    W2T    = (us*)alloc((ll)8 * 65536 * 2);
    us*    W3T    = (us*)alloc((ll)8 * 65536 * 2);
    float* ZF     = (float*)alloc((ll)8 * 65536 * 4);
    float* ZC     = (float*)alloc((ll)8 * 65536 * 4);
    float* XZF    = (float*)alloc((ll)8 * 65536 * 4);
    float* WAF    = (float*)alloc((ll)8 * 65536 * 4);
    float* WBF    = (float*)alloc((ll)8 * 65536 * 4);
    float* KVP    = (float*)alloc((ll)8 * NCHUNK * 16384 * 4);
    float* ZP     = (float*)alloc((ll)8 * NCHUNK * 256 * 4);
    float* KV     = (float*)alloc((ll)8 * 16384 * 4);
    float* PW     = (float*)alloc((ll)8 * 16384 * 4);
    us*    PWT    = (us*)alloc((ll)8 * 16384 * 2);
    float* HM     = (float*)alloc(64 * 4);
    float* SC     = (float*)alloc(64 * 4);
    int*   BAR    = (int*)alloc(256);
    float* ALPHA  = (float*)alloc(30000 * 4);
    float* ATT    = (float*)alloc((ll)NSEQ * 512 * 4);
    us*    ATTP   = (us*)alloc((ll)NSEQ * 512 * 2);
    us*    QK2B   = (us*)ATT;                     // alias: ATT dead after attn1 (30000*512 us)

    float* OUT  = (float*)d_out;
    float* ENC  = OUT;
    float* ARAW = OUT + (ll)NSEQ * DMODEL;

    // ---- prep
    trans_f2b<<<dim3(48, 32, 1), 256, 0, stream>>>(qkv_w, QKVWT, 1024, 1536, 0, 0);
    trans_f2b<<<dim3(32, 16, 1), 256, 0, stream>>>(out_w, OUTWT, 512, 1024, 0, 0);
    trans_f2b<<<dim3(8, 32, 1), 256, 0, stream>>>(wq_w, WQKT, 1024, 256, 0, 0);
    trans_f2b<<<dim3(8, 32, 1), 256, 0, stream>>>(wk_w, WQKT + (ll)256 * 1024, 1024, 256, 0, 0);
    trans_f2b<<<dim3(32, 32, 1), 256, 0, stream>>>(wv_w, WVT, 1024, 1024, 0, 0);
    concat_bias<<<1, 256, 0, stream>>>(wq_b, wk_b, WQKB);
    dense_pad_b<<<NPAD, 256, 0, stream>>>(dense, DENSEP);

    // ---- QKV projection -> per-head bf16 Q,K,V (q pre-scaled by 1/8)
    bgemm<3><<<dim3(12, 236, 1), 256, 0, stream>>>(DENSEP, QKVWT, nullptr, QKVH,
        nullptr, nullptr, nullptr, NPAD, 1536, 1024, 1024, 1024, 0, 0, NPAD, 1536, 0);

    // ---- landmarks
    landmark_mean_b<<<2048, 64, 0, stream>>>(Qh, QL);
    landmark_mean_b<<<2048, 64, 0, stream>>>(Kh, KL);
    f2b_vec<<<512, 256, 0, stream>>>(QL, QLB, 131072);
    f2b_vec<<<512, 256, 0, stream>>>(KL, KLB, 131072);

    // ---- attn2 (fp32) + denom
    gemm_k<1, 0><<<dim3(4, 2, 8), 256, 0, stream>>>(QL, KL, A2, LM, LM, DHEAD,
        DHEAD, DHEAD, LM, LM * DHEAD, LM * DHEAD, LM * LM, 1.f, 0.f);
    rowsoftmax256<<<2048, 256, 0, stream>>>(A2);
    colrow_max<<<8, 256, 0, stream>>>(A2, HM);
    denom_fin<<<1, 1, 0, stream>>>(HM, SC);
    pinv_init<<<2048, 256, 0, stream>>>(A2, SC, XN, ZN, ZT);

    // ---- persistent fused pinv (6 bf16 iterations, 24 stages, 1 launch)
    zero_f32<<<1, 256, 0, stream>>>((float*)BAR, 64);
    pinv_fused<<<PINV_BLOCKS, 256, 0, stream>>>(XN, ZN, ZT, ZN2, ZT2, XZN, W1T, W2T, W3T, BAR);

    // ---- final fp32 refinement iteration (ends at ZN after 6 swaps)
    zwiden<<<2048, 256, 0, stream>>>(ZN, ZF);
    gemm_k<0, 0><<<dim3(4, 2, 8), 256, 0, stream>>>(A2, ZF, XZF, LM, LM, LM,
        LM, LM, LM, 65536, 65536, 65536, 1.f, 0.f);
    seven_i_minus<<<2048, 256, 0, stream>>>(XZF, WAF);
    gemm_k<0, 4><<<dim3(4, 2, 8), 256, 0, stream>>>(XZF, WAF, WBF, LM, LM, LM,
        LM, LM, LM, 65536, 65536, 65536, 1.f, 15.f);
    gemm_k<0, 4><<<dim3(4, 2, 8), 256, 0, stream>>>(XZF, WBF, WAF, LM, LM, LM,
        LM, LM, LM, 65536, 65536, 65536, 1.f, 13.f);
    gemm_k<0, 0><<<dim3(4, 2, 8), 256, 0, stream>>>(ZF, WAF, ZC, LM, LM, LM,
        LM, LM, LM, 65536, 65536, 65536, 0.25f, 0.f);

    // ---- V transpose, fused attn3, KV
    trans_b2b<<<dim3(2, 944, 8), 256, 0, stream>>>(Vh, VT, NPAD, 64, (ll)NPAD * 64, (ll)64 * NPAD);
    attn3_fused<<<dim3(NCHUNK, 8), 256, 0, stream>>>(QLB, Kh, VT, KVP, ZP);
    kv_reduce2<<<512, 256, 0, stream>>>(KVP, ZP, KV);

    // ---- PW = pinv(attn2) @ KV ; PWT
    gemm_k<0, 0><<<dim3(1, 2, 8), 256, 0, stream>>>(ZC, KV, PW, LM, DHEAD, LM,
        LM, DHEAD, DHEAD, 65536, 16384, 16384, 1.f, 0.f);
    trans_f2b<<<dim3(2, 8, 8), 256, 0, stream>>>(PW, PWT, 256, 64, 16384, 16384);

    // ---- conv residual, fused attn1 (+conv add) -> ATTP bf16
    conv_res<<<dim3(7500, 8), 256, 0, stream>>>(Vh, conv_w, ATT);
    attn1_fused<<<dim3(235, 8), 256, 0, stream>>>(Qh, KLB, PWT, ATT, ATTP);

    // ---- out projection + bias + dense residual -> ENC fp32 (d_out) + ENCB bf16
    bgemm<2><<<dim3(8, 235, 1), 256, 0, stream>>>(ATTP, OUTWT, ENC, ENCB,
        out_b, dense, nullptr, NSEQ, 1024, 512, 512, 512, 1024, 1024, NSEQ, 1024, 0);

    // ---- merged q2|k2 projection (bf16 out, [row][512] layout)
    bgemm<10><<<dim3(4, 235, 1), 256, 0, stream>>>(ENCB, WQKT, nullptr, QK2B,
        WQKB, nullptr, nullptr, NSEQ, 512, 1024, 1024, 1024, 512, 0, NSEQ, 512, 0);

    // ---- edges -> A_raw -> alpha
    zero_f32<<<(NSEQ + 255) / 256, 256, 0, stream>>>(ARAW, NSEQ);
    edge_scores_b<<<(E + 3) / 4, 256, 0, stream>>>(ei, adj, QK2B, ARAW, E);
    softmax30k_stats<<<1, 1024, 0, stream>>>(ARAW, SC);
    alpha_kernel<<<(NSEQ + 255) / 256, 256, 0, stream>>>(ARAW, SC, ALPHA);

    // ---- fused value + gating (reads ENC in place, writes xo)
    bgemm<11><<<dim3(8, 235, 1), 256, 0, stream>>>(DENSEP + (ll)FPAD * 1024, WVT, OUT,
        nullptr, wv_b, nullptr, ALPHA, NSEQ, 1024, 1024, 1024, 1024, 1024, 0, NSEQ, 1024, 0);
}